// Round 2
// baseline (799.581 us; speedup 1.0000x reference)
//
#include <hip/hip_runtime.h>
#include <hip/hip_bf16.h>
#include <math.h>

// VectorQuantizer: z [8,256,32,32] f32, codebook [8192,256] f32
// outputs (flat f32): z_q [2097152] NCHW, idx [8192] (as float), loss, perplexity
#define KC 8192
#define DD 256
#define NP 8192
#define ZQ_ELEMS 2097152
#define MARGIN 4e-3f

// ws layout (bytes)
#define OFF_ABIG 0u           // bf16 [8192][512]  (Zh | Zl)
#define OFF_BBIG 8388608u     // bf16 [8192][512]  (Wh | Wl)
#define OFF_NRM  16777216u    // f32 [8192]
#define OFF_WSQ  16809984u    // f32 [8192]
#define OFF_ZSQ  16842752u    // f32 [8192]
#define OFF_PV1  16875520u    // f32 [64][8192]
#define OFF_PV2  18972672u    // f32 [64][8192]
#define OFF_PK1  21069824u    // i32 [64][8192]
#define OFF_IDX  23166976u    // i32 [8192]
#define OFF_FLAG 23199744u    // i32 [8192]
#define OFF_HIST 23232512u    // i32 [8192]
#define OFF_LOSS 23265280u    // f64 [1]

typedef __attribute__((ext_vector_type(8))) short bf16x8;
typedef __attribute__((ext_vector_type(4))) float f32x4;
typedef __attribute__((address_space(3))) void as3_void;
typedef const __attribute__((address_space(1))) void as1_cvoid;

#define GLOAD16(g, l) __builtin_amdgcn_global_load_lds((as1_cvoid*)(g), (as3_void*)(l), 16, 0, 0)

__device__ inline double waveReduceD(double v) {
#pragma unroll
    for (int off = 32; off; off >>= 1) v += __shfl_down(v, off, 64);
    return v;
}

static __device__ inline unsigned short f2bf(float f) {
    __hip_bfloat16 h = __float2bfloat16(f);  // RNE
    return *(unsigned short*)&h;
}
static __device__ inline float bf2f(unsigned short u) {
    unsigned v = ((unsigned)u) << 16;
    float f;
    __builtin_memcpy(&f, &v, 4);
    return f;
}

// one block per code row: normalize (same math as round-1, which passed),
// wsq from rounded w, nrm, and bf16 hi/lo split into Bbig
__global__ __launch_bounds__(256) void prep_w(
    const float* __restrict__ cb, unsigned short* __restrict__ Bbig,
    float* __restrict__ nrm, float* __restrict__ wsq) {
    __shared__ double lred[4];
    __shared__ float mh;
    int k = blockIdx.x, t = threadIdx.x;
    float c = cb[k * DD + t];
    double s = waveReduceD((double)c * (double)c);
    int lane = t & 63, wid = t >> 6;
    if (lane == 0) lred[wid] = s;
    __syncthreads();
    if (t == 0) {
        double tot = lred[0] + lred[1] + lred[2] + lred[3];
        float nf = sqrtf((float)tot);
        mh = fmaxf(nf, 1e-12f);
    }
    __syncthreads();
    float wv = c / mh;
    unsigned short hi = f2bf(wv);
    unsigned short lo = f2bf(wv - bf2f(hi));
    Bbig[k * 512 + t] = hi;
    Bbig[k * 512 + 256 + t] = lo;
    if (t == 0) nrm[k] = mh;
    __syncthreads();
    double s2 = waveReduceD((double)wv * (double)wv);
    if (lane == 0) lred[wid] = s2;
    __syncthreads();
    if (t == 0) wsq[k] = (float)(lred[0] + lred[1] + lred[2] + lred[3]);
}

// one block per point: zsq + bf16 hi/lo split into Abig (transpose from NCHW)
__global__ __launch_bounds__(256) void prep_z(
    const float* __restrict__ z, unsigned short* __restrict__ Abig,
    float* __restrict__ zsq) {
    __shared__ double lred[4];
    int n = blockIdx.x, t = threadIdx.x;
    int b = n >> 10, hw = n & 1023;
    float v = z[(b * DD + t) * 1024 + hw];
    unsigned short hi = f2bf(v);
    unsigned short lo = f2bf(v - bf2f(hi));
    Abig[n * 512 + t] = hi;
    Abig[n * 512 + 256 + t] = lo;
    double s = waveReduceD((double)v * (double)v);
    int lane = t & 63, wid = t >> 6;
    if (lane == 0) lred[wid] = s;
    __syncthreads();
    if (t == 0) zsq[n] = (float)(lred[0] + lred[1] + lred[2] + lred[3]);
}

// MFMA GEMM (3-product bf16 split, logical K=768) + per-row top-2 epilogue.
// grid (64 n-tiles, 64 k-tiles), 256 threads, 128x128 tile, BK=32.
__global__ __launch_bounds__(256) void gemm_top2(
    const unsigned short* __restrict__ Abig, const unsigned short* __restrict__ Bbig,
    const float* __restrict__ wsq, const float* __restrict__ zsq,
    float* __restrict__ pv1, float* __restrict__ pv2, int* __restrict__ pk1) {
    __shared__ unsigned short sAB[8192];  // sA [128][32] @0, sB [128][32] @4096

    int t = threadIdx.x;
    int l = t & 63, wid = t >> 6;
    int wr = wid >> 1, wc = wid & 1;
    int n0 = blockIdx.x * 128;
    int k0c = blockIdx.y * 128;

    f32x4 acc[4][4];
#pragma unroll
    for (int m = 0; m < 4; ++m)
#pragma unroll
        for (int n = 0; n < 4; ++n) acc[m][n] = (f32x4){0.f, 0.f, 0.f, 0.f};

    // staging geometry: tile byte off = t*16 (issue0) and t*16+4096 (issue1)
    int bo0 = t * 16, bo1 = t * 16 + 4096;
    int rowA0 = bo0 >> 6, kk0 = (bo0 & 63) >> 1;
    int rowA1 = bo1 >> 6, kk1 = (bo1 & 63) >> 1;
    int ldsA0 = wid * 1024, ldsA1 = wid * 1024 + 4096;

    for (int kt = 0; kt < 24; ++kt) {
        int aoff = ((kt < 16) ? 0 : 256) + (kt & 7) * 32;
        int boff = ((kt >= 8 && kt < 16) ? 256 : 0) + (kt & 7) * 32;
        __syncthreads();  // previous compute done; safe to overwrite LDS
        GLOAD16(Abig + (n0 + rowA0) * 512 + aoff + kk0, &sAB[ldsA0 >> 1]);
        GLOAD16(Abig + (n0 + rowA1) * 512 + aoff + kk1, &sAB[ldsA1 >> 1]);
        GLOAD16(Bbig + (k0c + rowA0) * 512 + boff + kk0, &sAB[(8192 + ldsA0) >> 1]);
        GLOAD16(Bbig + (k0c + rowA1) * 512 + boff + kk1, &sAB[(8192 + ldsA1) >> 1]);
        __syncthreads();  // drains vmcnt; tile visible

        bf16x8 af[4], bfr[4];
#pragma unroll
        for (int m = 0; m < 4; ++m)
            af[m] = *(const bf16x8*)&sAB[(wr * 64 + m * 16 + (l & 15)) * 32 + ((l >> 4) << 3)];
#pragma unroll
        for (int n = 0; n < 4; ++n)
            bfr[n] = *(const bf16x8*)&sAB[4096 + (wc * 64 + n * 16 + (l & 15)) * 32 + ((l >> 4) << 3)];
#pragma unroll
        for (int m = 0; m < 4; ++m)
#pragma unroll
            for (int n = 0; n < 4; ++n)
                acc[m][n] = __builtin_amdgcn_mfma_f32_16x16x32_bf16(af[m], bfr[n], acc[m][n], 0, 0, 0);
    }
    __syncthreads();  // all LDS reads done before reuse

    // epilogue: distances + per-row top-2 over this block's 128 cols
    float zs[4][4];
#pragma unroll
    for (int m = 0; m < 4; ++m)
#pragma unroll
        for (int r = 0; r < 4; ++r)
            zs[m][r] = zsq[n0 + wr * 64 + m * 16 + ((l >> 4) << 2) + r];
    float ws4[4];
#pragma unroll
    for (int n = 0; n < 4; ++n)
        ws4[n] = wsq[k0c + wc * 64 + n * 16 + (l & 15)];

    float* lv1 = (float*)sAB;          // [128][2]
    float* lv2 = lv1 + 256;            // [128][2]
    int* lk1 = (int*)(lv2 + 256);      // [128][2]

#pragma unroll
    for (int m = 0; m < 4; ++m) {
#pragma unroll
        for (int r = 0; r < 4; ++r) {
            float v1 = 3.4e38f, v2 = 3.4e38f;
            int k1 = 0;
#pragma unroll
            for (int n = 0; n < 4; ++n) {
                float dv = (zs[m][r] + ws4[n]) - 2.0f * acc[m][n][r];
                int col = k0c + wc * 64 + n * 16 + (l & 15);
                if (dv < v1) { v2 = v1; v1 = dv; k1 = col; }
                else if (dv < v2) v2 = dv;
            }
#pragma unroll
            for (int mask = 1; mask <= 8; mask <<= 1) {
                float ov1 = __shfl_xor(v1, mask, 64);
                int ok1 = __shfl_xor(k1, mask, 64);
                float ov2 = __shfl_xor(v2, mask, 64);
                if (ov1 < v1) { v2 = fminf(v1, ov2); v1 = ov1; k1 = ok1; }
                else { v2 = fminf(v2, ov1); }
            }
            if ((l & 15) == 0) {
                int row = wr * 64 + m * 16 + ((l >> 4) << 2) + r;
                lv1[row * 2 + wc] = v1;
                lv2[row * 2 + wc] = v2;
                lk1[row * 2 + wc] = k1;
            }
        }
    }
    __syncthreads();
    if (t < 128) {
        float a1 = lv1[t * 2], b1 = lv1[t * 2 + 1];
        float a2 = lv2[t * 2], b2 = lv2[t * 2 + 1];
        int ak = lk1[t * 2], bk = lk1[t * 2 + 1];
        float v1, v2;
        int k1;
        if (a1 <= b1) { v1 = a1; k1 = ak; v2 = fminf(a2, b1); }
        else { v1 = b1; k1 = bk; v2 = fminf(a1, b2); }
        pv1[blockIdx.y * NP + n0 + t] = v1;
        pv2[blockIdx.y * NP + n0 + t] = v2;
        pk1[blockIdx.y * NP + n0 + t] = k1;
    }
}

// merge 64 partials per row; flag ambiguous rows for exact rescore
__global__ __launch_bounds__(256) void merge_top2(
    const float* __restrict__ pv1, const float* __restrict__ pv2,
    const int* __restrict__ pk1, int* __restrict__ idxw, int* __restrict__ flag) {
    int n = blockIdx.x * 256 + threadIdx.x;
    float gv1 = 3.4e38f, gv2 = 3.4e38f;
    int gk1 = 0;
    for (int ct = 0; ct < 64; ++ct) {
        float v1 = pv1[ct * NP + n];
        if (v1 < gv1) {
            gv2 = fminf(gv1, pv2[ct * NP + n]);
            gv1 = v1;
            gk1 = pk1[ct * NP + n];
        } else {
            gv2 = fminf(gv2, v1);
        }
    }
    idxw[n] = gk1;
    flag[n] = (gv2 - gv1 < MARGIN) ? 1 : 0;
}

// exact fp32 rescore of flagged rows (round-1 association: sequential-d fp32)
__global__ __launch_bounds__(256) void rescore(
    const float* __restrict__ z, const float* __restrict__ cb,
    const float* __restrict__ nrm, const float* __restrict__ wsq,
    const float* __restrict__ zsq, const int* __restrict__ flag,
    int* __restrict__ idxw) {
    int n = blockIdx.x;
    if (!flag[n]) return;
    __shared__ float sz[256];
    __shared__ float rv[256];
    __shared__ int rk[256];
    int t = threadIdx.x;
    int b = n >> 10, hw = n & 1023;
    sz[t] = z[(b * DD + t) * 1024 + hw];
    __syncthreads();
    const float4* z4 = (const float4*)sz;
    float zq = zsq[n];
    float bv = 3.4e38f;
    int bk = 0x7fffffff;
    for (int c = 0; c < 32; ++c) {
        int k = c * 256 + t;
        const float4* w4 = (const float4*)&cb[(size_t)k * DD];
        float dot = 0.f;
#pragma unroll 8
        for (int i = 0; i < 64; ++i) {
            float4 cc = w4[i], zz = z4[i];
            dot += zz.x * cc.x;
            dot += zz.y * cc.y;
            dot += zz.z * cc.z;
            dot += zz.w * cc.w;
        }
        dot /= nrm[k];
        float dv = (zq + wsq[k]) - 2.0f * dot;
        if (dv < bv || (dv == bv && k < bk)) { bv = dv; bk = k; }
    }
    rv[t] = bv;
    rk[t] = bk;
    __syncthreads();
    for (int s = 128; s; s >>= 1) {
        if (t < s) {
            if (rv[t + s] < rv[t] || (rv[t + s] == rv[t] && rk[t + s] < rk[t])) {
                rv[t] = rv[t + s];
                rk[t] = rk[t + s];
            }
        }
        __syncthreads();
    }
    if (t == 0) idxw[n] = rk[0];
}

// final idx out (float) + histogram
__global__ __launch_bounds__(256) void hist_idx(
    const int* __restrict__ idxw, float* __restrict__ out, int* __restrict__ hist) {
    int n = blockIdx.x * 256 + threadIdx.x;
    int k = idxw[n];
    out[ZQ_ELEMS + n] = (float)k;
    atomicAdd(&hist[k], 1);
}

// z_q gather (w = cb/nrm, identical rounding to prep_w) + loss partial
__global__ __launch_bounds__(256) void gather_loss(
    const float* __restrict__ z, const float* __restrict__ cb,
    const float* __restrict__ nrm, const int* __restrict__ idxw,
    float* __restrict__ out, double* __restrict__ lossd) {
    __shared__ double lred[4];
    int e = blockIdx.x * 256 + threadIdx.x;
    int b = e >> 18, d = (e >> 10) & 255, hw = e & 1023;
    int n = (b << 10) + hw;
    int k = idxw[n];
    float wv = cb[k * DD + d] / nrm[k];
    out[e] = wv;
    float df = wv - z[e];
    float sq = df * df;
    double s = waveReduceD((double)sq);
    int lane = threadIdx.x & 63, wid = threadIdx.x >> 6;
    if (lane == 0) lred[wid] = s;
    __syncthreads();
    if (threadIdx.x == 0)
        atomicAdd(lossd, lred[0] + lred[1] + lred[2] + lred[3]);
}

__global__ __launch_bounds__(256) void finalize_kernel(
    const int* __restrict__ hist, const double* __restrict__ lossd,
    float* __restrict__ out) {
    __shared__ double lred[4];
    int t = threadIdx.x;
    double s = 0.0;
    for (int i = t; i < KC; i += 256) {
        float p = (float)hist[i] * (1.0f / 8192.0f);
        float lg = logf(p + 1e-10f);
        s += (double)(p * lg);
    }
    s = waveReduceD(s);
    int lane = t & 63, wid = t >> 6;
    if (lane == 0) lred[wid] = s;
    __syncthreads();
    if (t == 0) {
        double tot = lred[0] + lred[1] + lred[2] + lred[3];
        float m = (float)(lossd[0] / (double)ZQ_ELEMS);
        out[ZQ_ELEMS + NP] = m + 0.25f * m;
        out[ZQ_ELEMS + NP + 1] = expf(-(float)tot);
    }
}

extern "C" void kernel_launch(void* const* d_in, const int* in_sizes, int n_in,
                              void* d_out, int out_size, void* d_ws, size_t ws_size,
                              hipStream_t stream) {
    const float* z = (const float*)d_in[0];
    const float* cb = (const float*)d_in[1];
    float* out = (float*)d_out;
    char* ws = (char*)d_ws;

    unsigned short* Abig = (unsigned short*)(ws + OFF_ABIG);
    unsigned short* Bbig = (unsigned short*)(ws + OFF_BBIG);
    float* nrm = (float*)(ws + OFF_NRM);
    float* wsq = (float*)(ws + OFF_WSQ);
    float* zsq = (float*)(ws + OFF_ZSQ);
    float* pv1 = (float*)(ws + OFF_PV1);
    float* pv2 = (float*)(ws + OFF_PV2);
    int* pk1 = (int*)(ws + OFF_PK1);
    int* idxw = (int*)(ws + OFF_IDX);
    int* flag = (int*)(ws + OFF_FLAG);
    int* hist = (int*)(ws + OFF_HIST);
    double* lossd = (double*)(ws + OFF_LOSS);

    hipMemsetAsync(ws + OFF_HIST, 0, 32768 + 8, stream);

    prep_w<<<KC, 256, 0, stream>>>(cb, Bbig, nrm, wsq);
    prep_z<<<NP, 256, 0, stream>>>(z, Abig, zsq);
    gemm_top2<<<dim3(64, 64), 256, 0, stream>>>(Abig, Bbig, wsq, zsq, pv1, pv2, pk1);
    merge_top2<<<NP / 256, 256, 0, stream>>>(pv1, pv2, pk1, idxw, flag);
    rescore<<<NP, 256, 0, stream>>>(z, cb, nrm, wsq, zsq, flag, idxw);
    hist_idx<<<NP / 256, 256, 0, stream>>>(idxw, out, hist);
    gather_loss<<<ZQ_ELEMS / 256, 256, 0, stream>>>(z, cb, nrm, idxw, out, lossd);
    finalize_kernel<<<1, 256, 0, stream>>>(hist, lossd, out);
}

// Round 3
// 425.453 us; speedup vs baseline: 1.8794x; 1.8794x over previous
//
#include <hip/hip_runtime.h>
#include <hip/hip_bf16.h>
#include <math.h>

// VectorQuantizer: z [8,256,32,32] f32, codebook [8192,256] f32
// outputs (flat f32): z_q [2097152] NCHW, idx [8192] (as float), loss, perplexity
#define KC 8192
#define DD 256
#define NP 8192
#define ZQ_ELEMS 2097152
#define MARGIN 4e-3f

// ws layout (bytes)
#define OFF_ABIG 0u           // bf16 [8192][512]  (Zh | Zl)
#define OFF_BBIG 8388608u     // bf16 [8192][512]  (Wh | Wl)
#define OFF_NRM  16777216u    // f32 [8192]
#define OFF_WSQ  16809984u    // f32 [8192]
#define OFF_ZSQ  16842752u    // f32 [8192]
#define OFF_PV1  16875520u    // f32 [64][8192]
#define OFF_PV2  18972672u    // f32 [64][8192]
#define OFF_PK1  21069824u    // i32 [64][8192]
#define OFF_IDX  23166976u    // i32 [8192]
#define OFF_FLAG 23199744u    // i32 [8192]
#define OFF_HIST 23232512u    // i32 [8192]
#define OFF_LOSS 23265280u    // f64 [1]
#define OFF_PACK 23265288u    // u64 [8192]
#define OFF_LIST 23330824u    // i32 [8192]
#define OFF_NFLG 23363592u    // i32 [1]

typedef __attribute__((ext_vector_type(8))) short bf16x8;
typedef __attribute__((ext_vector_type(4))) float f32x4;
typedef __attribute__((address_space(3))) void as3_void;
typedef const __attribute__((address_space(1))) void as1_cvoid;

#define GLOAD16(g, l) __builtin_amdgcn_global_load_lds((as1_cvoid*)(g), (as3_void*)(l), 16, 0, 0)

__device__ inline double waveReduceD(double v) {
#pragma unroll
    for (int off = 32; off; off >>= 1) v += __shfl_down(v, off, 64);
    return v;
}

static __device__ inline unsigned short f2bf(float f) {
    __hip_bfloat16 h = __float2bfloat16(f);  // RNE
    return *(unsigned short*)&h;
}
static __device__ inline float bf2f(unsigned short u) {
    unsigned v = ((unsigned)u) << 16;
    float f;
    __builtin_memcpy(&f, &v, 4);
    return f;
}

// one block per code row: normalize, wsq, nrm, bf16 hi/lo split
__global__ __launch_bounds__(256) void prep_w(
    const float* __restrict__ cb, unsigned short* __restrict__ Bbig,
    float* __restrict__ nrm, float* __restrict__ wsq) {
    __shared__ double lred[4];
    __shared__ float mh;
    int k = blockIdx.x, t = threadIdx.x;
    float c = cb[k * DD + t];
    double s = waveReduceD((double)c * (double)c);
    int lane = t & 63, wid = t >> 6;
    if (lane == 0) lred[wid] = s;
    __syncthreads();
    if (t == 0) {
        double tot = lred[0] + lred[1] + lred[2] + lred[3];
        float nf = sqrtf((float)tot);
        mh = fmaxf(nf, 1e-12f);
    }
    __syncthreads();
    float wv = c / mh;
    unsigned short hi = f2bf(wv);
    unsigned short lo = f2bf(wv - bf2f(hi));
    Bbig[k * 512 + t] = hi;
    Bbig[k * 512 + 256 + t] = lo;
    if (t == 0) nrm[k] = mh;
    __syncthreads();
    double s2 = waveReduceD((double)wv * (double)wv);
    if (lane == 0) lred[wid] = s2;
    __syncthreads();
    if (t == 0) wsq[k] = (float)(lred[0] + lred[1] + lred[2] + lred[3]);
}

// one block per point: zsq + bf16 hi/lo split (transpose from NCHW)
__global__ __launch_bounds__(256) void prep_z(
    const float* __restrict__ z, unsigned short* __restrict__ Abig,
    float* __restrict__ zsq) {
    __shared__ double lred[4];
    int n = blockIdx.x, t = threadIdx.x;
    int b = n >> 10, hw = n & 1023;
    float v = z[(b * DD + t) * 1024 + hw];
    unsigned short hi = f2bf(v);
    unsigned short lo = f2bf(v - bf2f(hi));
    Abig[n * 512 + t] = hi;
    Abig[n * 512 + 256 + t] = lo;
    double s = waveReduceD((double)v * (double)v);
    int lane = t & 63, wid = t >> 6;
    if (lane == 0) lred[wid] = s;
    __syncthreads();
    if (t == 0) zsq[n] = (float)(lred[0] + lred[1] + lred[2] + lred[3]);
}

// MFMA GEMM (3-product bf16 split, logical K=768) + per-row top-2 epilogue.
__global__ __launch_bounds__(256) void gemm_top2(
    const unsigned short* __restrict__ Abig, const unsigned short* __restrict__ Bbig,
    const float* __restrict__ wsq, const float* __restrict__ zsq,
    float* __restrict__ pv1, float* __restrict__ pv2, int* __restrict__ pk1) {
    __shared__ unsigned short sAB[8192];  // sA [128][32] @0, sB [128][32] @4096

    int t = threadIdx.x;
    int l = t & 63, wid = t >> 6;
    int wr = wid >> 1, wc = wid & 1;
    int n0 = blockIdx.x * 128;
    int k0c = blockIdx.y * 128;

    f32x4 acc[4][4];
#pragma unroll
    for (int m = 0; m < 4; ++m)
#pragma unroll
        for (int n = 0; n < 4; ++n) acc[m][n] = (f32x4){0.f, 0.f, 0.f, 0.f};

    int bo0 = t * 16, bo1 = t * 16 + 4096;
    int rowA0 = bo0 >> 6, kk0 = (bo0 & 63) >> 1;
    int rowA1 = bo1 >> 6, kk1 = (bo1 & 63) >> 1;
    int ldsA0 = wid * 1024, ldsA1 = wid * 1024 + 4096;

    for (int kt = 0; kt < 24; ++kt) {
        int aoff = ((kt < 16) ? 0 : 256) + (kt & 7) * 32;
        int boff = ((kt >= 8 && kt < 16) ? 256 : 0) + (kt & 7) * 32;
        __syncthreads();
        GLOAD16(Abig + (n0 + rowA0) * 512 + aoff + kk0, &sAB[ldsA0 >> 1]);
        GLOAD16(Abig + (n0 + rowA1) * 512 + aoff + kk1, &sAB[ldsA1 >> 1]);
        GLOAD16(Bbig + (k0c + rowA0) * 512 + boff + kk0, &sAB[(8192 + ldsA0) >> 1]);
        GLOAD16(Bbig + (k0c + rowA1) * 512 + boff + kk1, &sAB[(8192 + ldsA1) >> 1]);
        __syncthreads();

        bf16x8 af[4], bfr[4];
#pragma unroll
        for (int m = 0; m < 4; ++m)
            af[m] = *(const bf16x8*)&sAB[(wr * 64 + m * 16 + (l & 15)) * 32 + ((l >> 4) << 3)];
#pragma unroll
        for (int n = 0; n < 4; ++n)
            bfr[n] = *(const bf16x8*)&sAB[4096 + (wc * 64 + n * 16 + (l & 15)) * 32 + ((l >> 4) << 3)];
#pragma unroll
        for (int m = 0; m < 4; ++m)
#pragma unroll
            for (int n = 0; n < 4; ++n)
                acc[m][n] = __builtin_amdgcn_mfma_f32_16x16x32_bf16(af[m], bfr[n], acc[m][n], 0, 0, 0);
    }
    __syncthreads();

    float zs[4][4];
#pragma unroll
    for (int m = 0; m < 4; ++m)
#pragma unroll
        for (int r = 0; r < 4; ++r)
            zs[m][r] = zsq[n0 + wr * 64 + m * 16 + ((l >> 4) << 2) + r];
    float ws4[4];
#pragma unroll
    for (int n = 0; n < 4; ++n)
        ws4[n] = wsq[k0c + wc * 64 + n * 16 + (l & 15)];

    float* lv1 = (float*)sAB;          // [128][2]
    float* lv2 = lv1 + 256;            // [128][2]
    int* lk1 = (int*)(lv2 + 256);      // [128][2]

#pragma unroll
    for (int m = 0; m < 4; ++m) {
#pragma unroll
        for (int r = 0; r < 4; ++r) {
            float v1 = 3.4e38f, v2 = 3.4e38f;
            int k1 = 0;
#pragma unroll
            for (int n = 0; n < 4; ++n) {
                float dv = (zs[m][r] + ws4[n]) - 2.0f * acc[m][n][r];
                int col = k0c + wc * 64 + n * 16 + (l & 15);
                if (dv < v1) { v2 = v1; v1 = dv; k1 = col; }
                else if (dv < v2) v2 = dv;
            }
#pragma unroll
            for (int mask = 1; mask <= 8; mask <<= 1) {
                float ov1 = __shfl_xor(v1, mask, 64);
                int ok1 = __shfl_xor(k1, mask, 64);
                float ov2 = __shfl_xor(v2, mask, 64);
                if (ov1 < v1) { v2 = fminf(v1, ov2); v1 = ov1; k1 = ok1; }
                else { v2 = fminf(v2, ov1); }
            }
            if ((l & 15) == 0) {
                int row = wr * 64 + m * 16 + ((l >> 4) << 2) + r;
                lv1[row * 2 + wc] = v1;
                lv2[row * 2 + wc] = v2;
                lk1[row * 2 + wc] = k1;
            }
        }
    }
    __syncthreads();
    if (t < 128) {
        float a1 = lv1[t * 2], b1 = lv1[t * 2 + 1];
        float a2 = lv2[t * 2], b2 = lv2[t * 2 + 1];
        int ak = lk1[t * 2], bk = lk1[t * 2 + 1];
        float v1, v2;
        int k1;
        if (a1 <= b1) { v1 = a1; k1 = ak; v2 = fminf(a2, b1); }
        else { v1 = b1; k1 = bk; v2 = fminf(a1, b2); }
        pv1[blockIdx.y * NP + n0 + t] = v1;
        pv2[blockIdx.y * NP + n0 + t] = v2;
        pk1[blockIdx.y * NP + n0 + t] = k1;
    }
}

// merge 64 partials per row; compact ambiguous rows for exact rescore
__global__ __launch_bounds__(256) void merge_top2(
    const float* __restrict__ pv1, const float* __restrict__ pv2,
    const int* __restrict__ pk1, int* __restrict__ idxw, int* __restrict__ flag,
    int* __restrict__ list, int* __restrict__ nflag,
    unsigned long long* __restrict__ packed) {
    int n = blockIdx.x * 256 + threadIdx.x;
    float gv1 = 3.4e38f, gv2 = 3.4e38f;
    int gk1 = 0;
    for (int ct = 0; ct < 64; ++ct) {
        float v1 = pv1[ct * NP + n];
        if (v1 < gv1) {
            gv2 = fminf(gv1, pv2[ct * NP + n]);
            gv1 = v1;
            gk1 = pk1[ct * NP + n];
        } else {
            gv2 = fminf(gv2, v1);
        }
    }
    idxw[n] = gk1;
    int f = (gv2 - gv1 < MARGIN) ? 1 : 0;
    flag[n] = f;
    if (f) {
        packed[n] = 0xFFFFFFFFFFFFFFFFull;
        int pos = atomicAdd(nflag, 1);
        list[pos] = n;
    }
}

// exact fp32 rescore of flagged rows, parallel over K chunks.
// grid (256, 32): block (i, c) grid-strides flagged list, handles codes c*256..+255
__global__ __launch_bounds__(256) void rescore_par(
    const float* __restrict__ z, const float* __restrict__ cb,
    const float* __restrict__ nrm, const float* __restrict__ wsq,
    const float* __restrict__ zsq, const int* __restrict__ list,
    const int* __restrict__ nflag, unsigned long long* __restrict__ packed) {
    __shared__ float sz[256];
    __shared__ float rv[256];
    __shared__ int rk[256];
    int nf = *nflag;
    int t = threadIdx.x;
    int k = blockIdx.y * 256 + t;
    const float4* w4 = (const float4*)&cb[(size_t)k * DD];
    float nr = nrm[k], wq = wsq[k];
    for (int ii = blockIdx.x; ii < nf; ii += 256) {
        int n = list[ii];
        int b = n >> 10, hw = n & 1023;
        sz[t] = z[(b * DD + t) * 1024 + hw];
        __syncthreads();
        const float4* z4 = (const float4*)sz;
        float dot = 0.f;
#pragma unroll 8
        for (int i = 0; i < 64; ++i) {
            float4 cc = w4[i], zz = z4[i];
            dot += zz.x * cc.x;
            dot += zz.y * cc.y;
            dot += zz.z * cc.z;
            dot += zz.w * cc.w;
        }
        dot /= nr;
        float dv = (zsq[n] + wq) - 2.0f * dot;
        rv[t] = dv;
        rk[t] = k;
        __syncthreads();
        for (int s = 128; s; s >>= 1) {
            if (t < s) {
                if (rv[t + s] < rv[t] || (rv[t + s] == rv[t] && rk[t + s] < rk[t])) {
                    rv[t] = rv[t + s];
                    rk[t] = rk[t + s];
                }
            }
            __syncthreads();
        }
        if (t == 0) {
            unsigned bits = __float_as_uint(rv[0]);
            bits = (bits & 0x80000000u) ? ~bits : (bits | 0x80000000u);  // monotonic
            unsigned long long pk = ((unsigned long long)bits << 32) | (unsigned)rk[0];
            atomicMin(packed + n, pk);
        }
        __syncthreads();  // protect sz/rv/rk before next ii
    }
}

// copy rescored winners back
__global__ __launch_bounds__(256) void fix_idx(
    const int* __restrict__ flag, const unsigned long long* __restrict__ packed,
    int* __restrict__ idxw) {
    int n = blockIdx.x * 256 + threadIdx.x;
    if (flag[n]) idxw[n] = (int)(packed[n] & 0xFFFFFFFFull);
}

// final idx out (float) + histogram
__global__ __launch_bounds__(256) void hist_idx(
    const int* __restrict__ idxw, float* __restrict__ out, int* __restrict__ hist) {
    int n = blockIdx.x * 256 + threadIdx.x;
    int k = idxw[n];
    out[ZQ_ELEMS + n] = (float)k;
    atomicAdd(&hist[k], 1);
}

// z_q gather (w = cb/nrm, identical rounding to prep_w) + loss partial
__global__ __launch_bounds__(256) void gather_loss(
    const float* __restrict__ z, const float* __restrict__ cb,
    const float* __restrict__ nrm, const int* __restrict__ idxw,
    float* __restrict__ out, double* __restrict__ lossd) {
    __shared__ double lred[4];
    int e = blockIdx.x * 256 + threadIdx.x;
    int b = e >> 18, d = (e >> 10) & 255, hw = e & 1023;
    int n = (b << 10) + hw;
    int k = idxw[n];
    float wv = cb[k * DD + d] / nrm[k];
    out[e] = wv;
    float df = wv - z[e];
    float sq = df * df;
    double s = waveReduceD((double)sq);
    int lane = threadIdx.x & 63, wid = threadIdx.x >> 6;
    if (lane == 0) lred[wid] = s;
    __syncthreads();
    if (threadIdx.x == 0)
        atomicAdd(lossd, lred[0] + lred[1] + lred[2] + lred[3]);
}

__global__ __launch_bounds__(256) void finalize_kernel(
    const int* __restrict__ hist, const double* __restrict__ lossd,
    float* __restrict__ out) {
    __shared__ double lred[4];
    int t = threadIdx.x;
    double s = 0.0;
    for (int i = t; i < KC; i += 256) {
        float p = (float)hist[i] * (1.0f / 8192.0f);
        float lg = logf(p + 1e-10f);
        s += (double)(p * lg);
    }
    s = waveReduceD(s);
    int lane = t & 63, wid = t >> 6;
    if (lane == 0) lred[wid] = s;
    __syncthreads();
    if (t == 0) {
        double tot = lred[0] + lred[1] + lred[2] + lred[3];
        float m = (float)(lossd[0] / (double)ZQ_ELEMS);
        out[ZQ_ELEMS + NP] = m + 0.25f * m;
        out[ZQ_ELEMS + NP + 1] = expf(-(float)tot);
    }
}

extern "C" void kernel_launch(void* const* d_in, const int* in_sizes, int n_in,
                              void* d_out, int out_size, void* d_ws, size_t ws_size,
                              hipStream_t stream) {
    const float* z = (const float*)d_in[0];
    const float* cb = (const float*)d_in[1];
    float* out = (float*)d_out;
    char* ws = (char*)d_ws;

    unsigned short* Abig = (unsigned short*)(ws + OFF_ABIG);
    unsigned short* Bbig = (unsigned short*)(ws + OFF_BBIG);
    float* nrm = (float*)(ws + OFF_NRM);
    float* wsq = (float*)(ws + OFF_WSQ);
    float* zsq = (float*)(ws + OFF_ZSQ);
    float* pv1 = (float*)(ws + OFF_PV1);
    float* pv2 = (float*)(ws + OFF_PV2);
    int* pk1 = (int*)(ws + OFF_PK1);
    int* idxw = (int*)(ws + OFF_IDX);
    int* flag = (int*)(ws + OFF_FLAG);
    int* hist = (int*)(ws + OFF_HIST);
    double* lossd = (double*)(ws + OFF_LOSS);
    unsigned long long* packed = (unsigned long long*)(ws + OFF_PACK);
    int* list = (int*)(ws + OFF_LIST);
    int* nflag = (int*)(ws + OFF_NFLG);

    hipMemsetAsync(ws + OFF_HIST, 0, 32768 + 8, stream);
    hipMemsetAsync(ws + OFF_NFLG, 0, 4, stream);

    prep_w<<<KC, 256, 0, stream>>>(cb, Bbig, nrm, wsq);
    prep_z<<<NP, 256, 0, stream>>>(z, Abig, zsq);
    gemm_top2<<<dim3(64, 64), 256, 0, stream>>>(Abig, Bbig, wsq, zsq, pv1, pv2, pk1);
    merge_top2<<<NP / 256, 256, 0, stream>>>(pv1, pv2, pk1, idxw, flag, list, nflag, packed);
    rescore_par<<<dim3(256, 32), 256, 0, stream>>>(z, cb, nrm, wsq, zsq, list, nflag, packed);
    fix_idx<<<NP / 256, 256, 0, stream>>>(flag, packed, idxw);
    hist_idx<<<NP / 256, 256, 0, stream>>>(idxw, out, hist);
    gather_loss<<<ZQ_ELEMS / 256, 256, 0, stream>>>(z, cb, nrm, idxw, out, lossd);
    finalize_kernel<<<1, 256, 0, stream>>>(hist, lossd, out);
}

// Round 4
// 363.657 us; speedup vs baseline: 2.1987x; 1.1699x over previous
//
#include <hip/hip_runtime.h>
#include <hip/hip_bf16.h>
#include <math.h>

// VectorQuantizer: z [8,256,32,32] f32, codebook [8192,256] f32
// outputs (flat f32): z_q [2097152] NCHW, idx [8192] (as float), loss, perplexity
#define KC 8192
#define DD 256
#define NP 8192
#define ZQ_ELEMS 2097152
#define MARGIN 5e-4f

// ws layout (bytes)
#define OFF_ABIG 0u           // bf16 [8192][512]  (Zh | Zl)
#define OFF_BBIG 8388608u     // bf16 [8192][512]  (Wh | Wl)
#define OFF_NRM  16777216u    // f32 [8192]
#define OFF_WSQ  16809984u    // f32 [8192]
#define OFF_ZSQ  16842752u    // f32 [8192]
#define OFF_PV1  16875520u    // f32 [64][8192]
#define OFF_PV2  18972672u    // f32 [64][8192]
#define OFF_PK1  21069824u    // i32 [64][8192]
#define OFF_IDX  23166976u    // i32 [8192]
#define OFF_FLAG 23199744u    // i32 [8192]
#define OFF_HIST 23232512u    // i32 [8192]
#define OFF_LOSS 23265280u    // f64 [1]
#define OFF_PACK 23265288u    // u64 [8192]
#define OFF_LIST 23330824u    // i32 [8192]
#define OFF_NFLG 23363592u    // i32 [1]

typedef __attribute__((ext_vector_type(8))) short bf16x8;
typedef __attribute__((ext_vector_type(4))) float f32x4;
typedef __attribute__((address_space(3))) void as3_void;
typedef const __attribute__((address_space(1))) void as1_cvoid;

#define GLOAD16(g, l) __builtin_amdgcn_global_load_lds((as1_cvoid*)(g), (as3_void*)(l), 16, 0, 0)

__device__ inline double waveReduceD(double v) {
#pragma unroll
    for (int off = 32; off; off >>= 1) v += __shfl_down(v, off, 64);
    return v;
}

static __device__ inline unsigned short f2bf(float f) {
    __hip_bfloat16 h = __float2bfloat16(f);  // RNE
    return *(unsigned short*)&h;
}
static __device__ inline float bf2f(unsigned short u) {
    unsigned v = ((unsigned)u) << 16;
    float f;
    __builtin_memcpy(&f, &v, 4);
    return f;
}

// one block per code row: normalize, wsq, nrm, bf16 hi/lo split.
// Also zeroes hist/nflag/lossd (replaces memsets; runs before any consumer).
__global__ __launch_bounds__(256) void prep_w(
    const float* __restrict__ cb, unsigned short* __restrict__ Bbig,
    float* __restrict__ nrm, float* __restrict__ wsq,
    int* __restrict__ hist, int* __restrict__ nflag, double* __restrict__ lossd) {
    __shared__ double lred[4];
    __shared__ float mh;
    int k = blockIdx.x, t = threadIdx.x;
    if (k < 32) hist[k * 256 + t] = 0;
    if (k == 32 && t == 0) { *nflag = 0; *lossd = 0.0; }
    float c = cb[k * DD + t];
    double s = waveReduceD((double)c * (double)c);
    int lane = t & 63, wid = t >> 6;
    if (lane == 0) lred[wid] = s;
    __syncthreads();
    if (t == 0) {
        double tot = lred[0] + lred[1] + lred[2] + lred[3];
        float nf = sqrtf((float)tot);
        mh = fmaxf(nf, 1e-12f);
    }
    __syncthreads();
    float wv = c / mh;
    unsigned short hi = f2bf(wv);
    unsigned short lo = f2bf(wv - bf2f(hi));
    Bbig[k * 512 + t] = hi;
    Bbig[k * 512 + 256 + t] = lo;
    if (t == 0) nrm[k] = mh;
    __syncthreads();
    double s2 = waveReduceD((double)wv * (double)wv);
    if (lane == 0) lred[wid] = s2;
    __syncthreads();
    if (t == 0) wsq[k] = (float)(lred[0] + lred[1] + lred[2] + lred[3]);
}

// one block per point: zsq + bf16 hi/lo split (transpose from NCHW)
__global__ __launch_bounds__(256) void prep_z(
    const float* __restrict__ z, unsigned short* __restrict__ Abig,
    float* __restrict__ zsq) {
    __shared__ double lred[4];
    int n = blockIdx.x, t = threadIdx.x;
    int b = n >> 10, hw = n & 1023;
    float v = z[(b * DD + t) * 1024 + hw];
    unsigned short hi = f2bf(v);
    unsigned short lo = f2bf(v - bf2f(hi));
    Abig[n * 512 + t] = hi;
    Abig[n * 512 + 256 + t] = lo;
    double s = waveReduceD((double)v * (double)v);
    int lane = t & 63, wid = t >> 6;
    if (lane == 0) lred[wid] = s;
    __syncthreads();
    if (t == 0) zsq[n] = (float)(lred[0] + lred[1] + lred[2] + lred[3]);
}

// MFMA GEMM (3-product bf16 split, logical K=768) + per-row top-2 epilogue.
// LDS chunk-XOR swizzle (T2): physical 16B-chunk p of row r holds logical
// chunk p ^ ((r>>1)&3); applied inverse on the global source (rule #21),
// forward on the ds_read side.
__global__ __launch_bounds__(256) void gemm_top2(
    const unsigned short* __restrict__ Abig, const unsigned short* __restrict__ Bbig,
    const float* __restrict__ wsq, const float* __restrict__ zsq,
    float* __restrict__ pv1, float* __restrict__ pv2, int* __restrict__ pk1) {
    __shared__ unsigned short sAB[8192];  // sA [128][32] @0, sB [128][32] @4096

    int t = threadIdx.x;
    int l = t & 63, wid = t >> 6;
    int wr = wid >> 1, wc = wid & 1;
    int n0 = blockIdx.x * 128;
    int k0c = blockIdx.y * 128;

    f32x4 acc[4][4];
#pragma unroll
    for (int m = 0; m < 4; ++m)
#pragma unroll
        for (int n = 0; n < 4; ++n) acc[m][n] = (f32x4){0.f, 0.f, 0.f, 0.f};

    int bo0 = t * 16, bo1 = t * 16 + 4096;
    int rowA0 = bo0 >> 6, rowA1 = bo1 >> 6;
    // inverse-swizzled source chunk (shorts offset within the 512-elem row)
    int kk0 = ((((bo0 >> 4) & 3) ^ ((rowA0 >> 1) & 3)) << 3);
    int kk1 = ((((bo1 >> 4) & 3) ^ ((rowA1 >> 1) & 3)) << 3);
    int ldsA0 = wid * 1024, ldsA1 = wid * 1024 + 4096;
    // swizzled read sub-chunk (shorts offset) — same for A and B fragments
    int subsw = (((l >> 4) ^ ((l >> 1) & 3)) << 3);

    for (int kt = 0; kt < 24; ++kt) {
        int aoff = ((kt < 16) ? 0 : 256) + (kt & 7) * 32;
        int boff = ((kt >= 8 && kt < 16) ? 256 : 0) + (kt & 7) * 32;
        __syncthreads();
        GLOAD16(Abig + (n0 + rowA0) * 512 + aoff + kk0, &sAB[ldsA0 >> 1]);
        GLOAD16(Abig + (n0 + rowA1) * 512 + aoff + kk1, &sAB[ldsA1 >> 1]);
        GLOAD16(Bbig + (k0c + rowA0) * 512 + boff + kk0, &sAB[(8192 + ldsA0) >> 1]);
        GLOAD16(Bbig + (k0c + rowA1) * 512 + boff + kk1, &sAB[(8192 + ldsA1) >> 1]);
        __syncthreads();

        bf16x8 af[4], bfr[4];
#pragma unroll
        for (int m = 0; m < 4; ++m)
            af[m] = *(const bf16x8*)&sAB[(wr * 64 + m * 16 + (l & 15)) * 32 + subsw];
#pragma unroll
        for (int n = 0; n < 4; ++n)
            bfr[n] = *(const bf16x8*)&sAB[4096 + (wc * 64 + n * 16 + (l & 15)) * 32 + subsw];
#pragma unroll
        for (int m = 0; m < 4; ++m)
#pragma unroll
            for (int n = 0; n < 4; ++n)
                acc[m][n] = __builtin_amdgcn_mfma_f32_16x16x32_bf16(af[m], bfr[n], acc[m][n], 0, 0, 0);
    }
    __syncthreads();

    float zs[4][4];
#pragma unroll
    for (int m = 0; m < 4; ++m)
#pragma unroll
        for (int r = 0; r < 4; ++r)
            zs[m][r] = zsq[n0 + wr * 64 + m * 16 + ((l >> 4) << 2) + r];
    float ws4[4];
#pragma unroll
    for (int n = 0; n < 4; ++n)
        ws4[n] = wsq[k0c + wc * 64 + n * 16 + (l & 15)];

    float* lv1 = (float*)sAB;          // [128][2]
    float* lv2 = lv1 + 256;            // [128][2]
    int* lk1 = (int*)(lv2 + 256);      // [128][2]

#pragma unroll
    for (int m = 0; m < 4; ++m) {
#pragma unroll
        for (int r = 0; r < 4; ++r) {
            float v1 = 3.4e38f, v2 = 3.4e38f;
            int k1 = 0;
#pragma unroll
            for (int n = 0; n < 4; ++n) {
                float dv = (zs[m][r] + ws4[n]) - 2.0f * acc[m][n][r];
                int col = k0c + wc * 64 + n * 16 + (l & 15);
                if (dv < v1) { v2 = v1; v1 = dv; k1 = col; }
                else if (dv < v2) v2 = dv;
            }
#pragma unroll
            for (int mask = 1; mask <= 8; mask <<= 1) {
                float ov1 = __shfl_xor(v1, mask, 64);
                int ok1 = __shfl_xor(k1, mask, 64);
                float ov2 = __shfl_xor(v2, mask, 64);
                if (ov1 < v1) { v2 = fminf(v1, ov2); v1 = ov1; k1 = ok1; }
                else { v2 = fminf(v2, ov1); }
            }
            if ((l & 15) == 0) {
                int row = wr * 64 + m * 16 + ((l >> 4) << 2) + r;
                lv1[row * 2 + wc] = v1;
                lv2[row * 2 + wc] = v2;
                lk1[row * 2 + wc] = k1;
            }
        }
    }
    __syncthreads();
    if (t < 128) {
        float a1 = lv1[t * 2], b1 = lv1[t * 2 + 1];
        float a2 = lv2[t * 2], b2 = lv2[t * 2 + 1];
        int ak = lk1[t * 2], bk = lk1[t * 2 + 1];
        float v1, v2;
        int k1;
        if (a1 <= b1) { v1 = a1; k1 = ak; v2 = fminf(a2, b1); }
        else { v1 = b1; k1 = bk; v2 = fminf(a1, b2); }
        pv1[blockIdx.y * NP + n0 + t] = v1;
        pv2[blockIdx.y * NP + n0 + t] = v2;
        pk1[blockIdx.y * NP + n0 + t] = k1;
    }
}

// merge 64 partials per row; compact ambiguous rows for exact rescore
__global__ __launch_bounds__(256) void merge_top2(
    const float* __restrict__ pv1, const float* __restrict__ pv2,
    const int* __restrict__ pk1, int* __restrict__ idxw, int* __restrict__ flag,
    int* __restrict__ list, int* __restrict__ nflag,
    unsigned long long* __restrict__ packed) {
    int n = blockIdx.x * 256 + threadIdx.x;
    float gv1 = 3.4e38f, gv2 = 3.4e38f;
    int gk1 = 0;
    for (int ct = 0; ct < 64; ++ct) {
        float v1 = pv1[ct * NP + n];
        if (v1 < gv1) {
            gv2 = fminf(gv1, pv2[ct * NP + n]);
            gv1 = v1;
            gk1 = pk1[ct * NP + n];
        } else {
            gv2 = fminf(gv2, v1);
        }
    }
    idxw[n] = gk1;
    int f = (gv2 - gv1 < MARGIN) ? 1 : 0;
    flag[n] = f;
    if (f) {
        packed[n] = 0xFFFFFFFFFFFFFFFFull;
        int pos = atomicAdd(nflag, 1);
        list[pos] = n;
    }
}

// exact fp32 rescore of flagged rows, wave-cooperative (lanes along D).
// grid (64, 32): block (i, c) strides flagged list, covers codes c*256..+255.
__global__ __launch_bounds__(256) void rescore_par(
    const float* __restrict__ z, const float* __restrict__ cb,
    const float* __restrict__ nrm, const float* __restrict__ wsq,
    const float* __restrict__ zsq, const int* __restrict__ list,
    const int* __restrict__ nflag, unsigned long long* __restrict__ packed) {
    __shared__ float sz[256];
    int nf = *nflag;
    int t = threadIdx.x;
    int lane = t & 63, wv = t >> 6;
    for (int ii = blockIdx.x; ii < nf; ii += 64) {
        int n = list[ii];
        int b = n >> 10, hw = n & 1023;
        __syncthreads();
        sz[t] = z[(b * DD + t) * 1024 + hw];
        __syncthreads();
        float4 zr = ((const float4*)sz)[lane];
        float zq = zsq[n];
        unsigned long long best = 0xFFFFFFFFFFFFFFFFull;
        int kbase = blockIdx.y * 256 + wv * 64;
        for (int j = 0; j < 64; ++j) {
            int k = kbase + j;
            float4 cc = *(const float4*)&cb[(size_t)k * DD + lane * 4];
            float p = (zr.x * cc.x + zr.y * cc.y) + (zr.z * cc.z + zr.w * cc.w);
#pragma unroll
            for (int off = 32; off; off >>= 1) p += __shfl_xor(p, off, 64);
            float dot = p / nrm[k];
            float dv = (zq + wsq[k]) - 2.0f * dot;
            unsigned bits = __float_as_uint(dv);
            bits = (bits & 0x80000000u) ? ~bits : (bits | 0x80000000u);
            unsigned long long pk = ((unsigned long long)bits << 32) | (unsigned)k;
            best = best < pk ? best : pk;
        }
        if (lane == 0) atomicMin(packed + n, best);
    }
}

// apply rescored winners + idx out (float) + histogram
__global__ __launch_bounds__(256) void fix_hist(
    const int* __restrict__ flag, const unsigned long long* __restrict__ packed,
    int* __restrict__ idxw, float* __restrict__ out, int* __restrict__ hist) {
    int n = blockIdx.x * 256 + threadIdx.x;
    int k = flag[n] ? (int)(packed[n] & 0xFFFFFFFFull) : idxw[n];
    idxw[n] = k;
    out[ZQ_ELEMS + n] = (float)k;
    atomicAdd(&hist[k], 1);
}

// z_q gather (w = cb/nrm, identical rounding to prep_w) + loss partial
__global__ __launch_bounds__(256) void gather_loss(
    const float* __restrict__ z, const float* __restrict__ cb,
    const float* __restrict__ nrm, const int* __restrict__ idxw,
    float* __restrict__ out, double* __restrict__ lossd) {
    __shared__ double lred[4];
    int e = blockIdx.x * 256 + threadIdx.x;
    int b = e >> 18, d = (e >> 10) & 255, hw = e & 1023;
    int n = (b << 10) + hw;
    int k = idxw[n];
    float wv = cb[k * DD + d] / nrm[k];
    out[e] = wv;
    float df = wv - z[e];
    float sq = df * df;
    double s = waveReduceD((double)sq);
    int lane = threadIdx.x & 63, wid = threadIdx.x >> 6;
    if (lane == 0) lred[wid] = s;
    __syncthreads();
    if (threadIdx.x == 0)
        atomicAdd(lossd, lred[0] + lred[1] + lred[2] + lred[3]);
}

__global__ __launch_bounds__(256) void finalize_kernel(
    const int* __restrict__ hist, const double* __restrict__ lossd,
    float* __restrict__ out) {
    __shared__ double lred[4];
    int t = threadIdx.x;
    double s = 0.0;
    for (int i = t; i < KC; i += 256) {
        float p = (float)hist[i] * (1.0f / 8192.0f);
        float lg = logf(p + 1e-10f);
        s += (double)(p * lg);
    }
    s = waveReduceD(s);
    int lane = t & 63, wid = t >> 6;
    if (lane == 0) lred[wid] = s;
    __syncthreads();
    if (t == 0) {
        double tot = lred[0] + lred[1] + lred[2] + lred[3];
        float m = (float)(lossd[0] / (double)ZQ_ELEMS);
        out[ZQ_ELEMS + NP] = m + 0.25f * m;
        out[ZQ_ELEMS + NP + 1] = expf(-(float)tot);
    }
}

extern "C" void kernel_launch(void* const* d_in, const int* in_sizes, int n_in,
                              void* d_out, int out_size, void* d_ws, size_t ws_size,
                              hipStream_t stream) {
    const float* z = (const float*)d_in[0];
    const float* cb = (const float*)d_in[1];
    float* out = (float*)d_out;
    char* ws = (char*)d_ws;

    unsigned short* Abig = (unsigned short*)(ws + OFF_ABIG);
    unsigned short* Bbig = (unsigned short*)(ws + OFF_BBIG);
    float* nrm = (float*)(ws + OFF_NRM);
    float* wsq = (float*)(ws + OFF_WSQ);
    float* zsq = (float*)(ws + OFF_ZSQ);
    float* pv1 = (float*)(ws + OFF_PV1);
    float* pv2 = (float*)(ws + OFF_PV2);
    int* pk1 = (int*)(ws + OFF_PK1);
    int* idxw = (int*)(ws + OFF_IDX);
    int* flag = (int*)(ws + OFF_FLAG);
    int* hist = (int*)(ws + OFF_HIST);
    double* lossd = (double*)(ws + OFF_LOSS);
    unsigned long long* packed = (unsigned long long*)(ws + OFF_PACK);
    int* list = (int*)(ws + OFF_LIST);
    int* nflag = (int*)(ws + OFF_NFLG);

    prep_w<<<KC, 256, 0, stream>>>(cb, Bbig, nrm, wsq, hist, nflag, lossd);
    prep_z<<<NP, 256, 0, stream>>>(z, Abig, zsq);
    gemm_top2<<<dim3(64, 64), 256, 0, stream>>>(Abig, Bbig, wsq, zsq, pv1, pv2, pk1);
    merge_top2<<<NP / 256, 256, 0, stream>>>(pv1, pv2, pk1, idxw, flag, list, nflag, packed);
    rescore_par<<<dim3(64, 32), 256, 0, stream>>>(z, cb, nrm, wsq, zsq, list, nflag, packed);
    fix_hist<<<NP / 256, 256, 0, stream>>>(flag, packed, idxw, out, hist);
    gather_loss<<<ZQ_ELEMS / 256, 256, 0, stream>>>(z, cb, nrm, idxw, out, lossd);
    finalize_kernel<<<1, 256, 0, stream>>>(hist, lossd, out);
}

// Round 5
// 273.737 us; speedup vs baseline: 2.9210x; 1.3285x over previous
//
#include <hip/hip_runtime.h>
#include <hip/hip_bf16.h>
#include <math.h>

// VectorQuantizer: z [8,256,32,32] f32, codebook [8192,256] f32
// outputs (flat f32): z_q [2097152] NCHW, idx [8192] (as float), loss, perplexity
#define KC 8192
#define DD 256
#define NP 8192
#define ZQ_ELEMS 2097152
#define MARGIN 5e-4f
#define NPART 16     // code-group partials (gemm grid.y)

// ws layout (bytes)
#define OFF_ABIG 0u           // bf16 [8192][512]  (Zh | Zl)
#define OFF_BBIG 8388608u     // bf16 [8192][512]  (Wh | Wl)
#define OFF_NRM  16777216u    // f32 [8192]
#define OFF_WSQ  16809984u    // f32 [8192]
#define OFF_ZSQ  16842752u    // f32 [8192]
#define OFF_PV1  16875520u    // f32 [16][8192]
#define OFF_PV2  18972672u    // f32 [16][8192]
#define OFF_LOSSP 20021248u   // f64 [512] (slack inside old PV2 region)
#define OFF_PK1  21069824u    // i32 [16][8192]
#define OFF_IDX  23166976u    // i32 [8192]
#define OFF_FLAG 23199744u    // i32 [8192]
#define OFF_HIST 23232512u    // i32 [8192]
#define OFF_PACK 23265288u    // u64 [8192]
#define OFF_LIST 23330824u    // i32 [8192]
#define OFF_NFLG 23363592u    // i32 [1]

typedef __attribute__((ext_vector_type(8))) short bf16x8;
typedef __attribute__((ext_vector_type(4))) float f32x4;
typedef __attribute__((address_space(3))) void as3_void;
typedef const __attribute__((address_space(1))) void as1_cvoid;

#define GLOAD16(g, l) __builtin_amdgcn_global_load_lds((as1_cvoid*)(g), (as3_void*)(l), 16, 0, 0)

__device__ inline double waveReduceD(double v) {
#pragma unroll
    for (int off = 32; off; off >>= 1) v += __shfl_down(v, off, 64);
    return v;
}

static __device__ inline unsigned short f2bf(float f) {
    __hip_bfloat16 h = __float2bfloat16(f);  // RNE
    return *(unsigned short*)&h;
}
static __device__ inline float bf2f(unsigned short u) {
    unsigned v = ((unsigned)u) << 16;
    float f;
    __builtin_memcpy(&f, &v, 4);
    return f;
}

// fused prep: blocks 0..8191 handle codebook rows (normalize, wsq, nrm, split,
// zero hist/nflag); blocks 8192..16383 handle z points (zsq, split, transpose).
__global__ __launch_bounds__(256) void prep(
    const float* __restrict__ cb, const float* __restrict__ z,
    unsigned short* __restrict__ Bbig, unsigned short* __restrict__ Abig,
    float* __restrict__ nrm, float* __restrict__ wsq, float* __restrict__ zsq,
    int* __restrict__ hist, int* __restrict__ nflag) {
    __shared__ double lred[4];
    __shared__ float mh;
    int bid = blockIdx.x, t = threadIdx.x;
    int lane = t & 63, wid = t >> 6;
    if (bid < KC) {
        int k = bid;
        if (k < 32) hist[k * 256 + t] = 0;
        if (k == 32 && t == 0) *nflag = 0;
        float c = cb[k * DD + t];
        double s = waveReduceD((double)c * (double)c);
        if (lane == 0) lred[wid] = s;
        __syncthreads();
        if (t == 0) {
            double tot = lred[0] + lred[1] + lred[2] + lred[3];
            float nf = sqrtf((float)tot);
            mh = fmaxf(nf, 1e-12f);
        }
        __syncthreads();
        float wv = c / mh;
        unsigned short hi = f2bf(wv);
        unsigned short lo = f2bf(wv - bf2f(hi));
        Bbig[k * 512 + t] = hi;
        Bbig[k * 512 + 256 + t] = lo;
        if (t == 0) nrm[k] = mh;
        __syncthreads();
        double s2 = waveReduceD((double)wv * (double)wv);
        if (lane == 0) lred[wid] = s2;
        __syncthreads();
        if (t == 0) wsq[k] = (float)(lred[0] + lred[1] + lred[2] + lred[3]);
    } else {
        int n = bid - KC;
        int b = n >> 10, hw = n & 1023;
        float v = z[(b * DD + t) * 1024 + hw];
        unsigned short hi = f2bf(v);
        unsigned short lo = f2bf(v - bf2f(hi));
        Abig[n * 512 + t] = hi;
        Abig[n * 512 + 256 + t] = lo;
        double s = waveReduceD((double)v * (double)v);
        if (lane == 0) lred[wid] = s;
        __syncthreads();
        if (t == 0) zsq[n] = (float)(lred[0] + lred[1] + lred[2] + lred[3]);
    }
}

// MFMA GEMM, orientation: A = W (codes, C-rows), B = Z (points, C-cols).
// C col = lane&15 -> point => per-point top-2 is an IN-THREAD running update
// across all 16 code-slots and 4 code-tiles; one shfl+LDS merge per block.
// grid (64 point-tiles, 16 code-groups); block covers 128 points x 512 codes.
__global__ __launch_bounds__(256) void gemm_top2(
    const unsigned short* __restrict__ Abig, const unsigned short* __restrict__ Bbig,
    const float* __restrict__ wsq, const float* __restrict__ zsq,
    float* __restrict__ pv1, float* __restrict__ pv2, int* __restrict__ pk1) {
    __shared__ unsigned short sAB[8192];  // sW [128][32] @0, sZ [128][32] @4096
    __shared__ float sWsq[512];

    int t = threadIdx.x;
    int l = t & 63, wid = t >> 6;
    int wr = wid >> 1, wc = wid & 1;     // wr: code-half, wc: point-half
    int n0 = blockIdx.x * 128;
    int kc0 = blockIdx.y * 512;

    sWsq[t] = wsq[kc0 + t];
    sWsq[256 + t] = wsq[kc0 + 256 + t];

    float zq[4];
#pragma unroll
    for (int nf = 0; nf < 4; ++nf) zq[nf] = zsq[n0 + wc * 64 + nf * 16 + (l & 15)];

    // staging geometry (chunk-XOR swizzle, inverse on source, forward on read)
    int bo0 = t * 16, bo1 = t * 16 + 4096;
    int row0 = bo0 >> 6, row1 = bo1 >> 6;
    int kk0 = (((t & 3) ^ ((row0 >> 1) & 3)) << 3);
    int kk1 = (((t & 3) ^ ((row1 >> 1) & 3)) << 3);
    int subsw = (((l >> 4) ^ ((l >> 1) & 3)) << 3);

    float v1[4], v2[4];
    int k1[4];
#pragma unroll
    for (int nf = 0; nf < 4; ++nf) { v1[nf] = 3.4e38f; v2[nf] = 3.4e38f; k1[nf] = 0; }

    for (int ct = 0; ct < 4; ++ct) {
        int kc = kc0 + ct * 128;
        f32x4 acc[4][4];
#pragma unroll
        for (int m = 0; m < 4; ++m)
#pragma unroll
            for (int n = 0; n < 4; ++n) acc[m][n] = (f32x4){0.f, 0.f, 0.f, 0.f};

        for (int kt = 0; kt < 24; ++kt) {
            // product order: [Zh.Wh][Zh.Wl][Zl.Wh]
            int zoff = ((kt < 16) ? 0 : 256) + (kt & 7) * 32;
            int woff = ((kt >= 8 && kt < 16) ? 256 : 0) + (kt & 7) * 32;
            __syncthreads();
            GLOAD16(Bbig + (kc + row0) * 512 + woff + kk0, &sAB[bo0 >> 1]);
            GLOAD16(Bbig + (kc + row1) * 512 + woff + kk1, &sAB[bo1 >> 1]);
            GLOAD16(Abig + (n0 + row0) * 512 + zoff + kk0, &sAB[(8192 + bo0) >> 1]);
            GLOAD16(Abig + (n0 + row1) * 512 + zoff + kk1, &sAB[(8192 + bo1) >> 1]);
            __syncthreads();

            bf16x8 af[4], bfr[4];
#pragma unroll
            for (int m = 0; m < 4; ++m)
                af[m] = *(const bf16x8*)&sAB[(wr * 64 + m * 16 + (l & 15)) * 32 + subsw];
#pragma unroll
            for (int n = 0; n < 4; ++n)
                bfr[n] = *(const bf16x8*)&sAB[4096 + (wc * 64 + n * 16 + (l & 15)) * 32 + subsw];
#pragma unroll
            for (int m = 0; m < 4; ++m)
#pragma unroll
                for (int n = 0; n < 4; ++n)
                    acc[m][n] = __builtin_amdgcn_mfma_f32_16x16x32_bf16(af[m], bfr[n], acc[m][n], 0, 0, 0);
        }
        // in-thread epilogue: rows of C are codes; lane's 4 cols are points
#pragma unroll
        for (int m = 0; m < 4; ++m) {
#pragma unroll
            for (int r = 0; r < 4; ++r) {
                int code = kc + wr * 64 + m * 16 + ((l >> 4) << 2) + r;
                float ws = sWsq[code - kc0];
#pragma unroll
                for (int nf = 0; nf < 4; ++nf) {
                    float dv = (zq[nf] + ws) - 2.0f * acc[m][nf][r];
                    if (dv < v1[nf]) { v2[nf] = v1[nf]; v1[nf] = dv; k1[nf] = code; }
                    else if (dv < v2[nf]) v2[nf] = dv;
                }
            }
        }
    }

    // cross-lane merge: 4 lanes (l>>4 groups) share each point; ties -> lower k
#pragma unroll
    for (int nf = 0; nf < 4; ++nf) {
#pragma unroll
        for (int mask = 16; mask <= 32; mask <<= 1) {
            float ov1 = __shfl_xor(v1[nf], mask, 64);
            float ov2 = __shfl_xor(v2[nf], mask, 64);
            int ok1 = __shfl_xor(k1[nf], mask, 64);
            bool take = (ov1 < v1[nf]) || (ov1 == v1[nf] && ok1 < k1[nf]);
            if (take) { v2[nf] = fminf(v1[nf], ov2); v1[nf] = ov1; k1[nf] = ok1; }
            else v2[nf] = fminf(v2[nf], ov1);
        }
    }
    __syncthreads();  // LDS reads done; alias sAB for merge
    float* sv1 = (float*)sAB;          // [128][2]
    float* sv2 = sv1 + 256;            // [128][2]
    int* sk1 = (int*)(sv2 + 256);      // [128][2]
    if ((l >> 4) == 0) {
#pragma unroll
        for (int nf = 0; nf < 4; ++nf) {
            int pt = wc * 64 + nf * 16 + (l & 15);
            sv1[pt * 2 + wr] = v1[nf];
            sv2[pt * 2 + wr] = v2[nf];
            sk1[pt * 2 + wr] = k1[nf];
        }
    }
    __syncthreads();
    if (t < 128) {
        float a1 = sv1[t * 2], b1 = sv1[t * 2 + 1];
        float a2 = sv2[t * 2], b2 = sv2[t * 2 + 1];
        int ak = sk1[t * 2], bk = sk1[t * 2 + 1];
        bool tb = (b1 < a1) || (b1 == a1 && bk < ak);
        float w1 = tb ? b1 : a1;
        int wk = tb ? bk : ak;
        float w2 = tb ? fminf(b2, a1) : fminf(a2, b1);
        pv1[blockIdx.y * NP + n0 + t] = w1;
        pv2[blockIdx.y * NP + n0 + t] = w2;
        pk1[blockIdx.y * NP + n0 + t] = wk;
    }
}

// merge 16 partials per row; compact ambiguous rows for exact rescore
__global__ __launch_bounds__(256) void merge_top2(
    const float* __restrict__ pv1, const float* __restrict__ pv2,
    const int* __restrict__ pk1, int* __restrict__ idxw, int* __restrict__ flag,
    int* __restrict__ list, int* __restrict__ nflag,
    unsigned long long* __restrict__ packed) {
    int n = blockIdx.x * 256 + threadIdx.x;
    float gv1 = 3.4e38f, gv2 = 3.4e38f;
    int gk1 = 0;
#pragma unroll
    for (int ct = 0; ct < NPART; ++ct) {
        float v1 = pv1[ct * NP + n];
        if (v1 < gv1) {
            gv2 = fminf(gv1, pv2[ct * NP + n]);
            gv1 = v1;
            gk1 = pk1[ct * NP + n];
        } else {
            gv2 = fminf(gv2, v1);
        }
    }
    idxw[n] = gk1;
    int f = (gv2 - gv1 < MARGIN) ? 1 : 0;
    flag[n] = f;
    if (f) {
        packed[n] = 0xFFFFFFFFFFFFFFFFull;
        int pos = atomicAdd(nflag, 1);
        list[pos] = n;
    }
}

// exact fp32 rescore of flagged rows, wave-cooperative (lanes along D).
// grid (64, 32): block (i, c) strides flagged list, covers codes c*256..+255.
__global__ __launch_bounds__(256) void rescore_par(
    const float* __restrict__ z, const float* __restrict__ cb,
    const float* __restrict__ nrm, const float* __restrict__ wsq,
    const float* __restrict__ zsq, const int* __restrict__ list,
    const int* __restrict__ nflag, unsigned long long* __restrict__ packed) {
    __shared__ float sz[256];
    int nf = *nflag;
    int t = threadIdx.x;
    int lane = t & 63, wv = t >> 6;
    for (int ii = blockIdx.x; ii < nf; ii += 64) {
        int n = list[ii];
        int b = n >> 10, hw = n & 1023;
        __syncthreads();
        sz[t] = z[(b * DD + t) * 1024 + hw];
        __syncthreads();
        float4 zr = ((const float4*)sz)[lane];
        float zq = zsq[n];
        unsigned long long best = 0xFFFFFFFFFFFFFFFFull;
        int kbase = blockIdx.y * 256 + wv * 64;
        for (int j = 0; j < 64; ++j) {
            int k = kbase + j;
            float4 cc = *(const float4*)&cb[(size_t)k * DD + lane * 4];
            float p = (zr.x * cc.x + zr.y * cc.y) + (zr.z * cc.z + zr.w * cc.w);
#pragma unroll
            for (int off = 32; off; off >>= 1) p += __shfl_xor(p, off, 64);
            float dot = p / nrm[k];
            float dv = (zq + wsq[k]) - 2.0f * dot;
            unsigned bits = __float_as_uint(dv);
            bits = (bits & 0x80000000u) ? ~bits : (bits | 0x80000000u);
            unsigned long long pk = ((unsigned long long)bits << 32) | (unsigned)k;
            best = best < pk ? best : pk;
        }
        if (lane == 0) atomicMin(packed + n, best);
    }
}

// apply rescored winners + idx out (float) + histogram
__global__ __launch_bounds__(256) void fix_hist(
    const int* __restrict__ flag, const unsigned long long* __restrict__ packed,
    int* __restrict__ idxw, float* __restrict__ out, int* __restrict__ hist) {
    int n = blockIdx.x * 256 + threadIdx.x;
    int k = flag[n] ? (int)(packed[n] & 0xFFFFFFFFull) : idxw[n];
    idxw[n] = k;
    out[ZQ_ELEMS + n] = (float)k;
    atomicAdd(&hist[k], 1);
}

// z_q gather (w = cb/nrm, identical rounding to prep) + per-block loss partial
__global__ __launch_bounds__(256) void gather_loss(
    const float* __restrict__ z, const float* __restrict__ cb,
    const float* __restrict__ nrm, const int* __restrict__ idxw,
    float* __restrict__ out, double* __restrict__ lossp) {
    __shared__ double lred[4];
    int t = threadIdx.x;
    int base = (blockIdx.x * 256 + t) * 16;
    double s = 0.0;
#pragma unroll
    for (int q = 0; q < 4; ++q) {
        int e = base + q * 4;
        int b = e >> 18, d = (e >> 10) & 255, hw = e & 1023;
        int n = (b << 10) + hw;
        float4 zv = *(const float4*)&z[e];
        float o[4];
#pragma unroll
        for (int j = 0; j < 4; ++j) {
            int k = idxw[n + j];
            o[j] = cb[k * DD + d] / nrm[k];
        }
        *(float4*)&out[e] = make_float4(o[0], o[1], o[2], o[3]);
        float d0 = o[0] - zv.x, d1 = o[1] - zv.y, d2 = o[2] - zv.z, d3 = o[3] - zv.w;
        s += (double)(d0 * d0) + (double)(d1 * d1) + (double)(d2 * d2) + (double)(d3 * d3);
    }
    s = waveReduceD(s);
    int lane = t & 63, wid = t >> 6;
    if (lane == 0) lred[wid] = s;
    __syncthreads();
    if (t == 0) lossp[blockIdx.x] = lred[0] + lred[1] + lred[2] + lred[3];
}

// single block: loss from 512 partials + perplexity from histogram
__global__ __launch_bounds__(256) void finalize_kernel(
    const int* __restrict__ hist, const double* __restrict__ lossp,
    float* __restrict__ out) {
    __shared__ double lred[4];
    __shared__ double lsum;
    int t = threadIdx.x;
    int lane = t & 63, wid = t >> 6;
    double ls = lossp[t] + lossp[t + 256];
    ls = waveReduceD(ls);
    if (lane == 0) lred[wid] = ls;
    __syncthreads();
    if (t == 0) lsum = lred[0] + lred[1] + lred[2] + lred[3];
    __syncthreads();
    double s = 0.0;
    for (int i = t; i < KC; i += 256) {
        float p = (float)hist[i] * (1.0f / 8192.0f);
        float lg = logf(p + 1e-10f);
        s += (double)(p * lg);
    }
    s = waveReduceD(s);
    if (lane == 0) lred[wid] = s;
    __syncthreads();
    if (t == 0) {
        double tot = lred[0] + lred[1] + lred[2] + lred[3];
        float m = (float)(lsum / (double)ZQ_ELEMS);
        out[ZQ_ELEMS + NP] = m + 0.25f * m;
        out[ZQ_ELEMS + NP + 1] = expf(-(float)tot);
    }
}

extern "C" void kernel_launch(void* const* d_in, const int* in_sizes, int n_in,
                              void* d_out, int out_size, void* d_ws, size_t ws_size,
                              hipStream_t stream) {
    const float* z = (const float*)d_in[0];
    const float* cb = (const float*)d_in[1];
    float* out = (float*)d_out;
    char* ws = (char*)d_ws;

    unsigned short* Abig = (unsigned short*)(ws + OFF_ABIG);
    unsigned short* Bbig = (unsigned short*)(ws + OFF_BBIG);
    float* nrm = (float*)(ws + OFF_NRM);
    float* wsq = (float*)(ws + OFF_WSQ);
    float* zsq = (float*)(ws + OFF_ZSQ);
    float* pv1 = (float*)(ws + OFF_PV1);
    float* pv2 = (float*)(ws + OFF_PV2);
    int* pk1 = (int*)(ws + OFF_PK1);
    int* idxw = (int*)(ws + OFF_IDX);
    int* flag = (int*)(ws + OFF_FLAG);
    int* hist = (int*)(ws + OFF_HIST);
    double* lossp = (double*)(ws + OFF_LOSSP);
    unsigned long long* packed = (unsigned long long*)(ws + OFF_PACK);
    int* list = (int*)(ws + OFF_LIST);
    int* nflag = (int*)(ws + OFF_NFLG);

    prep<<<2 * KC, 256, 0, stream>>>(cb, z, Bbig, Abig, nrm, wsq, zsq, hist, nflag);
    gemm_top2<<<dim3(64, NPART), 256, 0, stream>>>(Abig, Bbig, wsq, zsq, pv1, pv2, pk1);
    merge_top2<<<NP / 256, 256, 0, stream>>>(pv1, pv2, pk1, idxw, flag, list, nflag, packed);
    rescore_par<<<dim3(64, 32), 256, 0, stream>>>(z, cb, nrm, wsq, zsq, list, nflag, packed);
    fix_hist<<<NP / 256, 256, 0, stream>>>(flag, packed, idxw, out, hist);
    gather_loss<<<ZQ_ELEMS / (256 * 16), 256, 0, stream>>>(z, cb, nrm, idxw, out, lossp);
    finalize_kernel<<<1, 256, 0, stream>>>(hist, lossp, out);
}

// Round 6
// 217.403 us; speedup vs baseline: 3.6779x; 1.2591x over previous
//
#include <hip/hip_runtime.h>
#include <hip/hip_bf16.h>
#include <math.h>

// VectorQuantizer: z [8,256,32,32] f32, codebook [8192,256] f32
// outputs (flat f32): z_q [2097152] NCHW, idx [8192] (as float), loss, perplexity
#define KC 8192
#define DD 256
#define NP 8192
#define ZQ_ELEMS 2097152
#define MARGIN_S 2.5e-4f   // s-space (== 5e-4 in d-space, validated round 4/5)
#define NPART 32           // code-group partials (gemm grid.y)

// ws layout (bytes)
#define OFF_ABIG 0u           // bf16 [8192][512]  (Zh | Zl)  points
#define OFF_BBIG 8388608u     // bf16 [8192][512]  (Wh | Wl)  codes
#define OFF_NRM  16777216u    // f32 [8192]
#define OFF_WSQ  16809984u    // f32 [8192]
#define OFF_ZSQ  16842752u    // f32 [8192]
#define OFF_PV1  16875520u    // f32 [32][8192]
#define OFF_PV2  17924096u    // f32 [32][8192]
#define OFF_PK1  18972672u    // i32 [32][8192]
#define OFF_LOSSP 20021248u   // f64 [512]
#define OFF_IDX  20025344u    // i32 [8192]
#define OFF_FLAG 20058112u    // i32 [8192]
#define OFF_HIST 20090880u    // i32 [8192]
#define OFF_PACK 20123648u    // u64 [8192]
#define OFF_LIST 20189184u    // i32 [8192]
#define OFF_NFLG 20221952u    // i32 [1]

typedef __attribute__((ext_vector_type(8))) short bf16x8;
typedef __attribute__((ext_vector_type(4))) float f32x4;
typedef __attribute__((address_space(3))) void as3_void;
typedef const __attribute__((address_space(1))) void as1_cvoid;

#define GLOAD16(g, l) __builtin_amdgcn_global_load_lds((as1_cvoid*)(g), (as3_void*)(l), 16, 0, 0)

__device__ inline double waveReduceD(double v) {
#pragma unroll
    for (int off = 32; off; off >>= 1) v += __shfl_down(v, off, 64);
    return v;
}

static __device__ inline unsigned short f2bf(float f) {
    __hip_bfloat16 h = __float2bfloat16(f);  // RNE
    return *(unsigned short*)&h;
}
static __device__ inline float bf2f(unsigned short u) {
    unsigned v = ((unsigned)u) << 16;
    float f;
    __builtin_memcpy(&f, &v, 4);
    return f;
}

// fused prep: blocks 0..8191 codebook rows; blocks 8192..16383 z points.
__global__ __launch_bounds__(256) void prep(
    const float* __restrict__ cb, const float* __restrict__ z,
    unsigned short* __restrict__ Bbig, unsigned short* __restrict__ Abig,
    float* __restrict__ nrm, float* __restrict__ wsq, float* __restrict__ zsq,
    int* __restrict__ hist, int* __restrict__ nflag) {
    __shared__ double lred[4];
    __shared__ float mh;
    int bid = blockIdx.x, t = threadIdx.x;
    int lane = t & 63, wid = t >> 6;
    if (bid < KC) {
        int k = bid;
        if (k < 32) hist[k * 256 + t] = 0;
        if (k == 32 && t == 0) *nflag = 0;
        float c = cb[k * DD + t];
        double s = waveReduceD((double)c * (double)c);
        if (lane == 0) lred[wid] = s;
        __syncthreads();
        if (t == 0) {
            double tot = lred[0] + lred[1] + lred[2] + lred[3];
            float nf = sqrtf((float)tot);
            mh = fmaxf(nf, 1e-12f);
        }
        __syncthreads();
        float wv = c / mh;
        unsigned short hi = f2bf(wv);
        unsigned short lo = f2bf(wv - bf2f(hi));
        Bbig[k * 512 + t] = hi;
        Bbig[k * 512 + 256 + t] = lo;
        if (t == 0) nrm[k] = mh;
        __syncthreads();
        double s2 = waveReduceD((double)wv * (double)wv);
        if (lane == 0) lred[wid] = s2;
        __syncthreads();
        if (t == 0) wsq[k] = (float)(lred[0] + lred[1] + lred[2] + lred[3]);
    } else {
        int n = bid - KC;
        int b = n >> 10, hw = n & 1023;
        float v = z[(b * DD + t) * 1024 + hw];
        unsigned short hi = f2bf(v);
        unsigned short lo = f2bf(v - bf2f(hi));
        Abig[n * 512 + t] = hi;
        Abig[n * 512 + 256 + t] = lo;
        double s = waveReduceD((double)v * (double)v);
        if (lane == 0) lred[wid] = s;
        __syncthreads();
        if (t == 0) zsq[n] = (float)(lred[0] + lred[1] + lred[2] + lred[3]);
    }
}

// Deep-pipelined MFMA GEMM + top-2 screen.
// C[256 codes][256 points] per block; A = W (codes), B = Z (points).
// Quad-buffered LDS, stage depth 3, counted vmcnt(8) per K-tile, 1 barrier/K-tile.
// acc init = -wsq/2  =>  score dv = -acc = wsq/2 - dot (argmin == argmin d).
__global__ __launch_bounds__(512, 2) void gemm_top2(
    const unsigned short* __restrict__ Abig, const unsigned short* __restrict__ Bbig,
    const float* __restrict__ wsq,
    float* __restrict__ pv1, float* __restrict__ pv2, int* __restrict__ pk1) {
    // [buf 0..3][ W 256x32 (8192 sh) | Z 256x32 (8192 sh) ] = 128 KiB
    __shared__ unsigned short sAB[65536];

    int t = threadIdx.x;
    int l = t & 63, w = t >> 6;
    int wm = w >> 2, wn = w & 3;
    int kc0 = blockIdx.y * 256;   // code base (C rows)
    int n0 = blockIdx.x * 256;    // point base (C cols)

    // ---- staging geometry (chunk-XOR swizzle; proven 0-conflict) ----
    int row0 = t >> 2;            // rows 0..127 (j=0), +128 (j=1)
    int lsw = (((t & 3) ^ ((row0 >> 1) & 3)) << 3);  // inverse-swizzled src chunk (shorts)
    // frag-read swizzled sub-chunk (shorts)
    int subsw = (((l >> 4) ^ ((l >> 1) & 3)) << 3);

#define STAGE(kt_) do {                                                        \
    int p_ = (kt_) >> 3;                                                       \
    int zo_ = (p_ == 2 ? 256 : 0) + ((kt_) & 7) * 32;                          \
    int wo_ = (p_ == 1 ? 256 : 0) + ((kt_) & 7) * 32;                          \
    int b_ = ((kt_) & 3) * 16384;                                              \
    GLOAD16(Bbig + (size_t)(kc0 + row0) * 512 + wo_ + lsw, &sAB[b_ + t * 8]);  \
    GLOAD16(Bbig + (size_t)(kc0 + row0 + 128) * 512 + wo_ + lsw, &sAB[b_ + 4096 + t * 8]); \
    GLOAD16(Abig + (size_t)(n0 + row0) * 512 + zo_ + lsw, &sAB[b_ + 8192 + t * 8]); \
    GLOAD16(Abig + (size_t)(n0 + row0 + 128) * 512 + zo_ + lsw, &sAB[b_ + 12288 + t * 8]); \
} while (0)

    // accumulators: 8 m-frags (codes) x 4 n-frags (points); init = -wsq/2
    f32x4 acc[8][4];
#pragma unroll
    for (int mf = 0; mf < 8; ++mf) {
#pragma unroll
        for (int r = 0; r < 4; ++r) {
            float hv = -0.5f * wsq[kc0 + wm * 128 + mf * 16 + ((l >> 4) << 2) + r];
#pragma unroll
            for (int nf = 0; nf < 4; ++nf) acc[mf][nf][r] = hv;
        }
    }

#define KBODY(bufbase) do {                                                    \
    bf16x8 af[8], bfr[4];                                                      \
    _Pragma("unroll")                                                          \
    for (int mf = 0; mf < 8; ++mf)                                             \
        af[mf] = *(const bf16x8*)&sAB[(bufbase) + (wm * 128 + mf * 16 + (l & 15)) * 32 + subsw]; \
    _Pragma("unroll")                                                          \
    for (int nf = 0; nf < 4; ++nf)                                             \
        bfr[nf] = *(const bf16x8*)&sAB[(bufbase) + 8192 + (wn * 64 + nf * 16 + (l & 15)) * 32 + subsw]; \
    __builtin_amdgcn_s_setprio(1);                                             \
    _Pragma("unroll")                                                          \
    for (int mf = 0; mf < 8; ++mf)                                             \
        _Pragma("unroll")                                                      \
        for (int nf = 0; nf < 4; ++nf)                                         \
            acc[mf][nf] = __builtin_amdgcn_mfma_f32_16x16x32_bf16(af[mf], bfr[nf], acc[mf][nf], 0, 0, 0); \
    __builtin_amdgcn_s_setprio(0);                                             \
} while (0)

    // prologue: stage K-tiles 0,1,2 (12 loads/wave); wait tile 0 (8 left in flight)
    STAGE(0);
    STAGE(1);
    STAGE(2);
    asm volatile("s_waitcnt vmcnt(8)" ::: "memory");
    __builtin_amdgcn_s_barrier();
    asm volatile("" ::: "memory");

    // main loop: stage kt+3, compute kt, wait kt+1's loads (vmcnt 12->8), barrier
    for (int kt = 0; kt < 21; ++kt) {
        STAGE(kt + 3);
        KBODY((kt & 3) * 16384);
        asm volatile("s_waitcnt vmcnt(8)" ::: "memory");
        __builtin_amdgcn_s_barrier();
        asm volatile("" ::: "memory");
    }
    // epilogue drain: kt = 21, 22, 23
    KBODY(1 * 16384);
    asm volatile("s_waitcnt vmcnt(4)" ::: "memory");
    __builtin_amdgcn_s_barrier();
    asm volatile("" ::: "memory");
    KBODY(2 * 16384);
    asm volatile("s_waitcnt vmcnt(0)" ::: "memory");
    __builtin_amdgcn_s_barrier();
    asm volatile("" ::: "memory");
    KBODY(3 * 16384);

    // ---- top-2 screen epilogue (s-space: dv = -acc, smaller = better) ----
    float v1[4], v2[4];
    int k1[4];
#pragma unroll
    for (int nf = 0; nf < 4; ++nf) { v1[nf] = 3.4e38f; v2[nf] = 3.4e38f; k1[nf] = 0; }
#pragma unroll
    for (int mf = 0; mf < 8; ++mf) {
#pragma unroll
        for (int r = 0; r < 4; ++r) {
            int code = kc0 + wm * 128 + mf * 16 + ((l >> 4) << 2) + r;
#pragma unroll
            for (int nf = 0; nf < 4; ++nf) {
                float dv = -acc[mf][nf][r];
                bool lt = dv < v1[nf];
                v2[nf] = fminf(v2[nf], fmaxf(v1[nf], dv));
                v1[nf] = fminf(v1[nf], dv);
                k1[nf] = lt ? code : k1[nf];
            }
        }
    }
    // merge across the 4 row-groups (lanes l, l^16, l^32, l^48 share cols)
#pragma unroll
    for (int nf = 0; nf < 4; ++nf) {
#pragma unroll
        for (int mask = 16; mask <= 32; mask <<= 1) {
            float ov1 = __shfl_xor(v1[nf], mask, 64);
            float ov2 = __shfl_xor(v2[nf], mask, 64);
            int ok1 = __shfl_xor(k1[nf], mask, 64);
            bool take = (ov1 < v1[nf]) || (ov1 == v1[nf] && ok1 < k1[nf]);
            if (take) { v2[nf] = fminf(v1[nf], ov2); v1[nf] = ov1; k1[nf] = ok1; }
            else v2[nf] = fminf(v2[nf], ov1);
        }
    }
    __syncthreads();  // pipeline fully done; reuse LDS for cross-wave merge
    float* sv1 = (float*)sAB;            // [256][2]
    float* sv2 = sv1 + 512;              // [256][2]
    int* sk1 = (int*)(sv2 + 512);        // [256][2]
    if ((l >> 4) == 0) {
#pragma unroll
        for (int nf = 0; nf < 4; ++nf) {
            int col = wn * 64 + nf * 16 + l;
            sv1[col * 2 + wm] = v1[nf];
            sv2[col * 2 + wm] = v2[nf];
            sk1[col * 2 + wm] = k1[nf];
        }
    }
    __syncthreads();
    if (t < 256) {
        float a1 = sv1[t * 2], b1 = sv1[t * 2 + 1];
        float a2 = sv2[t * 2], b2 = sv2[t * 2 + 1];
        int ak = sk1[t * 2], bk = sk1[t * 2 + 1];
        bool tb = (b1 < a1) || (b1 == a1 && bk < ak);
        float w1 = tb ? b1 : a1;
        int wk = tb ? bk : ak;
        float w2 = tb ? fminf(b2, a1) : fminf(a2, b1);
        pv1[blockIdx.y * NP + n0 + t] = w1;
        pv2[blockIdx.y * NP + n0 + t] = w2;
        pk1[blockIdx.y * NP + n0 + t] = wk;
    }
#undef STAGE
#undef KBODY
}

// merge 32 partials per point; compact ambiguous rows for exact rescore
__global__ __launch_bounds__(256) void merge_top2(
    const float* __restrict__ pv1, const float* __restrict__ pv2,
    const int* __restrict__ pk1, int* __restrict__ idxw, int* __restrict__ flag,
    int* __restrict__ list, int* __restrict__ nflag,
    unsigned long long* __restrict__ packed) {
    int n = blockIdx.x * 256 + threadIdx.x;
    float gv1 = 3.4e38f, gv2 = 3.4e38f;
    int gk1 = 0;
#pragma unroll
    for (int ct = 0; ct < NPART; ++ct) {
        float v1 = pv1[ct * NP + n];
        if (v1 < gv1) {
            gv2 = fminf(gv1, pv2[ct * NP + n]);
            gv1 = v1;
            gk1 = pk1[ct * NP + n];
        } else {
            gv2 = fminf(gv2, v1);
        }
    }
    idxw[n] = gk1;
    int f = (gv2 - gv1 < MARGIN_S) ? 1 : 0;
    flag[n] = f;
    if (f) {
        packed[n] = 0xFFFFFFFFFFFFFFFFull;
        int pos = atomicAdd(nflag, 1);
        list[pos] = n;
    }
}

// exact fp32 rescore of flagged rows, wave-cooperative (lanes along D).
__global__ __launch_bounds__(256) void rescore_par(
    const float* __restrict__ z, const float* __restrict__ cb,
    const float* __restrict__ nrm, const float* __restrict__ wsq,
    const float* __restrict__ zsq, const int* __restrict__ list,
    const int* __restrict__ nflag, unsigned long long* __restrict__ packed) {
    __shared__ float sz[256];
    int nf = *nflag;
    int t = threadIdx.x;
    int lane = t & 63, wv = t >> 6;
    for (int ii = blockIdx.x; ii < nf; ii += 64) {
        int n = list[ii];
        int b = n >> 10, hw = n & 1023;
        __syncthreads();
        sz[t] = z[(b * DD + t) * 1024 + hw];
        __syncthreads();
        float4 zr = ((const float4*)sz)[lane];
        float zq = zsq[n];
        unsigned long long best = 0xFFFFFFFFFFFFFFFFull;
        int kbase = blockIdx.y * 256 + wv * 64;
        for (int j = 0; j < 64; ++j) {
            int k = kbase + j;
            float4 cc = *(const float4*)&cb[(size_t)k * DD + lane * 4];
            float p = (zr.x * cc.x + zr.y * cc.y) + (zr.z * cc.z + zr.w * cc.w);
#pragma unroll
            for (int off = 32; off; off >>= 1) p += __shfl_xor(p, off, 64);
            float dot = p / nrm[k];
            float dv = (zq + wsq[k]) - 2.0f * dot;
            unsigned bits = __float_as_uint(dv);
            bits = (bits & 0x80000000u) ? ~bits : (bits | 0x80000000u);
            unsigned long long pk = ((unsigned long long)bits << 32) | (unsigned)k;
            best = best < pk ? best : pk;
        }
        if (lane == 0) atomicMin(packed + n, best);
    }
}

// apply rescored winners + idx out (float) + histogram
__global__ __launch_bounds__(256) void fix_hist(
    const int* __restrict__ flag, const unsigned long long* __restrict__ packed,
    int* __restrict__ idxw, float* __restrict__ out, int* __restrict__ hist) {
    int n = blockIdx.x * 256 + threadIdx.x;
    int k = flag[n] ? (int)(packed[n] & 0xFFFFFFFFull) : idxw[n];
    idxw[n] = k;
    out[ZQ_ELEMS + n] = (float)k;
    atomicAdd(&hist[k], 1);
}

// z_q gather (w = cb/nrm, identical rounding to prep) + per-block loss partial
__global__ __launch_bounds__(256) void gather_loss(
    const float* __restrict__ z, const float* __restrict__ cb,
    const float* __restrict__ nrm, const int* __restrict__ idxw,
    float* __restrict__ out, double* __restrict__ lossp) {
    __shared__ double lred[4];
    int t = threadIdx.x;
    int base = (blockIdx.x * 256 + t) * 16;
    double s = 0.0;
#pragma unroll
    for (int q = 0; q < 4; ++q) {
        int e = base + q * 4;
        int b = e >> 18, d = (e >> 10) & 255, hw = e & 1023;
        int n = (b << 10) + hw;
        float4 zv = *(const float4*)&z[e];
        float o[4];
#pragma unroll
        for (int j = 0; j < 4; ++j) {
            int k = idxw[n + j];
            o[j] = cb[k * DD + d] / nrm[k];
        }
        *(float4*)&out[e] = make_float4(o[0], o[1], o[2], o[3]);
        float d0 = o[0] - zv.x, d1 = o[1] - zv.y, d2 = o[2] - zv.z, d3 = o[3] - zv.w;
        s += (double)(d0 * d0) + (double)(d1 * d1) + (double)(d2 * d2) + (double)(d3 * d3);
    }
    s = waveReduceD(s);
    int lane = t & 63, wid = t >> 6;
    if (lane == 0) lred[wid] = s;
    __syncthreads();
    if (t == 0) lossp[blockIdx.x] = lred[0] + lred[1] + lred[2] + lred[3];
}

// single block: loss from 512 partials + perplexity from histogram
__global__ __launch_bounds__(256) void finalize_kernel(
    const int* __restrict__ hist, const double* __restrict__ lossp,
    float* __restrict__ out) {
    __shared__ double lred[4];
    __shared__ double lsum;
    int t = threadIdx.x;
    int lane = t & 63, wid = t >> 6;
    double ls = lossp[t] + lossp[t + 256];
    ls = waveReduceD(ls);
    if (lane == 0) lred[wid] = ls;
    __syncthreads();
    if (t == 0) lsum = lred[0] + lred[1] + lred[2] + lred[3];
    __syncthreads();
    double s = 0.0;
    for (int i = t; i < KC; i += 256) {
        float p = (float)hist[i] * (1.0f / 8192.0f);
        float lg = logf(p + 1e-10f);
        s += (double)(p * lg);
    }
    s = waveReduceD(s);
    if (lane == 0) lred[wid] = s;
    __syncthreads();
    if (t == 0) {
        double tot = lred[0] + lred[1] + lred[2] + lred[3];
        float m = (float)(lsum / (double)ZQ_ELEMS);
        out[ZQ_ELEMS + NP] = m + 0.25f * m;
        out[ZQ_ELEMS + NP + 1] = expf(-(float)tot);
    }
}

extern "C" void kernel_launch(void* const* d_in, const int* in_sizes, int n_in,
                              void* d_out, int out_size, void* d_ws, size_t ws_size,
                              hipStream_t stream) {
    const float* z = (const float*)d_in[0];
    const float* cb = (const float*)d_in[1];
    float* out = (float*)d_out;
    char* ws = (char*)d_ws;

    unsigned short* Abig = (unsigned short*)(ws + OFF_ABIG);
    unsigned short* Bbig = (unsigned short*)(ws + OFF_BBIG);
    float* nrm = (float*)(ws + OFF_NRM);
    float* wsq = (float*)(ws + OFF_WSQ);
    float* zsq = (float*)(ws + OFF_ZSQ);
    float* pv1 = (float*)(ws + OFF_PV1);
    float* pv2 = (float*)(ws + OFF_PV2);
    int* pk1 = (int*)(ws + OFF_PK1);
    int* idxw = (int*)(ws + OFF_IDX);
    int* flag = (int*)(ws + OFF_FLAG);
    int* hist = (int*)(ws + OFF_HIST);
    double* lossp = (double*)(ws + OFF_LOSSP);
    unsigned long long* packed = (unsigned long long*)(ws + OFF_PACK);
    int* list = (int*)(ws + OFF_LIST);
    int* nflag = (int*)(ws + OFF_NFLG);

    prep<<<2 * KC, 256, 0, stream>>>(cb, z, Bbig, Abig, nrm, wsq, zsq, hist, nflag);
    gemm_top2<<<dim3(32, NPART), 512, 0, stream>>>(Abig, Bbig, wsq, pv1, pv2, pk1);
    merge_top2<<<NP / 256, 256, 0, stream>>>(pv1, pv2, pk1, idxw, flag, list, nflag, packed);
    rescore_par<<<dim3(64, 32), 256, 0, stream>>>(z, cb, nrm, wsq, zsq, list, nflag, packed);
    fix_hist<<<NP / 256, 256, 0, stream>>>(flag, packed, idxw, out, hist);
    gather_loss<<<ZQ_ELEMS / (256 * 16), 256, 0, stream>>>(z, cb, nrm, idxw, out, lossp);
    finalize_kernel<<<1, 256, 0, stream>>>(hist, lossp, out);
}

// Round 7
// 215.590 us; speedup vs baseline: 3.7088x; 1.0084x over previous
//
#include <hip/hip_runtime.h>
#include <hip/hip_bf16.h>
#include <math.h>

// VectorQuantizer: z [8,256,32,32] f32, codebook [8192,256] f32
// outputs (flat f32): z_q [2097152] NCHW, idx [8192] (as float), loss, perplexity
#define KC 8192
#define DD 256
#define NP 8192
#define ZQ_ELEMS 2097152
#define MARGIN_S 2.5e-4f   // s-space (== 5e-4 in d-space, validated round 4/5)
#define NPART 32           // code-group partials (gemm grid.y)

// ws layout (bytes)
#define OFF_ABIG 0u           // bf16 [8192][512]  (Zh | Zl)  points
#define OFF_BBIG 8388608u     // bf16 [8192][512]  (Wh | Wl)  codes
#define OFF_NRM  16777216u    // f32 [8192]
#define OFF_WSQ  16809984u    // f32 [8192]
#define OFF_ZSQ  16842752u    // f32 [8192]
#define OFF_PV1  16875520u    // f32 [32][8192]
#define OFF_PV2  17924096u    // f32 [32][8192]
#define OFF_PK1  18972672u    // i32 [32][8192]
#define OFF_LOSSP 20021248u   // f64 [512]
#define OFF_IDX  20025344u    // i32 [8192]
#define OFF_FLAG 20058112u    // i32 [8192]
#define OFF_HIST 20090880u    // i32 [8192]
#define OFF_PACK 20123648u    // u64 [8192]
#define OFF_LIST 20189184u    // i32 [8192]
#define OFF_NFLG 20221952u    // i32 [1]

typedef __attribute__((ext_vector_type(8))) short bf16x8;
typedef __attribute__((ext_vector_type(4))) float f32x4;
typedef __attribute__((address_space(3))) void as3_void;
typedef const __attribute__((address_space(1))) void as1_cvoid;

#define GLOAD16(g, l) __builtin_amdgcn_global_load_lds((as1_cvoid*)(g), (as3_void*)(l), 16, 0, 0)

__device__ inline double waveReduceD(double v) {
#pragma unroll
    for (int off = 32; off; off >>= 1) v += __shfl_down(v, off, 64);
    return v;
}

static __device__ inline unsigned short f2bf(float f) {
    __hip_bfloat16 h = __float2bfloat16(f);  // RNE
    return *(unsigned short*)&h;
}
static __device__ inline float bf2f(unsigned short u) {
    unsigned v = ((unsigned)u) << 16;
    float f;
    __builtin_memcpy(&f, &v, 4);
    return f;
}

// fused prep: blocks 0..8191 codebook rows; blocks 8192..16383 z points.
__global__ __launch_bounds__(256) void prep(
    const float* __restrict__ cb, const float* __restrict__ z,
    unsigned short* __restrict__ Bbig, unsigned short* __restrict__ Abig,
    float* __restrict__ nrm, float* __restrict__ wsq, float* __restrict__ zsq,
    int* __restrict__ hist, int* __restrict__ nflag) {
    __shared__ double lred[4];
    __shared__ float mh;
    int bid = blockIdx.x, t = threadIdx.x;
    int lane = t & 63, wid = t >> 6;
    if (bid < KC) {
        int k = bid;
        if (k < 32) hist[k * 256 + t] = 0;
        if (k == 32 && t == 0) *nflag = 0;
        float c = cb[k * DD + t];
        double s = waveReduceD((double)c * (double)c);
        if (lane == 0) lred[wid] = s;
        __syncthreads();
        if (t == 0) {
            double tot = lred[0] + lred[1] + lred[2] + lred[3];
            float nf = sqrtf((float)tot);
            mh = fmaxf(nf, 1e-12f);
            nrm[k] = mh;
            wsq[k] = (float)(tot / ((double)mh * (double)mh));
        }
        __syncthreads();
        float wv = c / mh;
        unsigned short hi = f2bf(wv);
        unsigned short lo = f2bf(wv - bf2f(hi));
        Bbig[k * 512 + t] = hi;
        Bbig[k * 512 + 256 + t] = lo;
    } else {
        int n = bid - KC;
        int b = n >> 10, hw = n & 1023;
        float v = z[(b * DD + t) * 1024 + hw];
        unsigned short hi = f2bf(v);
        unsigned short lo = f2bf(v - bf2f(hi));
        Abig[n * 512 + t] = hi;
        Abig[n * 512 + 256 + t] = lo;
        double s = waveReduceD((double)v * (double)v);
        if (lane == 0) lred[wid] = s;
        __syncthreads();
        if (t == 0) zsq[n] = (float)(lred[0] + lred[1] + lred[2] + lred[3]);
    }
}

// Deep-pipelined MFMA GEMM + top-2 screen, now with 4-phase per-K-tile
// interleave (m201 pattern): each phase {ds_read frag ∥ 1 stage-load ->
// barrier -> lgkmcnt(0) -> setprio MFMA cluster -> barrier}; counted
// vmcnt once per K-tile (8 main / 4,0 drain).
// C[256 codes][256 points] per block; A = W (codes), B = Z (points).
// acc init = -wsq/2  =>  score dv = -acc = wsq/2 - dot (argmin == argmin d).
__global__ __launch_bounds__(512, 2) void gemm_top2(
    const unsigned short* __restrict__ Abig, const unsigned short* __restrict__ Bbig,
    const float* __restrict__ wsq,
    float* __restrict__ pv1, float* __restrict__ pv2, int* __restrict__ pk1) {
    // [buf 0..3][ W 256x32 (8192 sh) | Z 256x32 (8192 sh) ] = 128 KiB
    __shared__ unsigned short sAB[65536];

    int t = threadIdx.x;
    int l = t & 63, w = t >> 6;
    int wm = w >> 2, wn = w & 3;
    int kc0 = blockIdx.y * 256;   // code base (C rows)
    int n0 = blockIdx.x * 256;    // point base (C cols)

    // staging geometry (chunk-XOR swizzle; proven 0-conflict)
    int row0 = t >> 2;            // rows 0..127 (+128 for second half)
    int lsw = (((t & 3) ^ ((row0 >> 1) & 3)) << 3);  // inverse-swizzled src chunk (shorts)
    int subsw = (((l >> 4) ^ ((l >> 1) & 3)) << 3);  // frag-read swizzled sub-chunk

#define STAGE1(kt_, piece) do {                                                \
    int p_ = (kt_) >> 3;                                                       \
    int zo_ = (p_ == 2 ? 256 : 0) + ((kt_) & 7) * 32;                          \
    int wo_ = (p_ == 1 ? 256 : 0) + ((kt_) & 7) * 32;                          \
    int b_ = ((kt_) & 3) * 16384;                                              \
    if ((piece) == 0) GLOAD16(Bbig + (size_t)(kc0 + row0) * 512 + wo_ + lsw, &sAB[b_ + t * 8]); \
    else if ((piece) == 1) GLOAD16(Bbig + (size_t)(kc0 + row0 + 128) * 512 + wo_ + lsw, &sAB[b_ + 4096 + t * 8]); \
    else if ((piece) == 2) GLOAD16(Abig + (size_t)(n0 + row0) * 512 + zo_ + lsw, &sAB[b_ + 8192 + t * 8]); \
    else GLOAD16(Abig + (size_t)(n0 + row0 + 128) * 512 + zo_ + lsw, &sAB[b_ + 12288 + t * 8]); \
} while (0)

#define STAGE4(kt_) do { STAGE1(kt_, 0); STAGE1(kt_, 1); STAGE1(kt_, 2); STAGE1(kt_, 3); } while (0)

#define LDA(bb, mf) (*(const bf16x8*)&sAB[(bb) + (wm * 128 + (mf) * 16 + (l & 15)) * 32 + subsw])
#define LDB(bb, nf) (*(const bf16x8*)&sAB[(bb) + 8192 + (wn * 64 + (nf) * 16 + (l & 15)) * 32 + subsw])

#define MFMA8(m0) do {                                                         \
    _Pragma("unroll")                                                          \
    for (int nf_ = 0; nf_ < 4; ++nf_)                                          \
        acc[m0][nf_] = __builtin_amdgcn_mfma_f32_16x16x32_bf16(aA_, bfr[nf_], acc[m0][nf_], 0, 0, 0); \
    _Pragma("unroll")                                                          \
    for (int nf_ = 0; nf_ < 4; ++nf_)                                          \
        acc[(m0) + 1][nf_] = __builtin_amdgcn_mfma_f32_16x16x32_bf16(aB_, bfr[nf_], acc[(m0) + 1][nf_], 0, 0, 0); \
} while (0)

#define KTILE(kt_, STEN, VMLINE) do {                                          \
    const int bb_ = ((kt_) & 3) * 16384;                                       \
    bf16x8 bfr[4];                                                             \
    bf16x8 aA_, aB_;                                                           \
    /* phase 0 */                                                              \
    aA_ = LDA(bb_, 0); aB_ = LDA(bb_, 1);                                      \
    bfr[0] = LDB(bb_, 0); bfr[1] = LDB(bb_, 1);                                \
    bfr[2] = LDB(bb_, 2); bfr[3] = LDB(bb_, 3);                                \
    if (STEN) STAGE1((kt_) + 3, 0);                                            \
    __builtin_amdgcn_s_barrier();                                              \
    asm volatile("s_waitcnt lgkmcnt(0)" ::: "memory");                         \
    __builtin_amdgcn_s_setprio(1); MFMA8(0); __builtin_amdgcn_s_setprio(0);    \
    __builtin_amdgcn_s_barrier();                                              \
    /* phase 1 */                                                              \
    aA_ = LDA(bb_, 2); aB_ = LDA(bb_, 3);                                      \
    if (STEN) STAGE1((kt_) + 3, 1);                                            \
    __builtin_amdgcn_s_barrier();                                              \
    asm volatile("s_waitcnt lgkmcnt(0)" ::: "memory");                         \
    __builtin_amdgcn_s_setprio(1); MFMA8(2); __builtin_amdgcn_s_setprio(0);    \
    __builtin_amdgcn_s_barrier();                                              \
    /* phase 2 */                                                              \
    aA_ = LDA(bb_, 4); aB_ = LDA(bb_, 5);                                      \
    if (STEN) STAGE1((kt_) + 3, 2);                                            \
    __builtin_amdgcn_s_barrier();                                              \
    asm volatile("s_waitcnt lgkmcnt(0)" ::: "memory");                         \
    __builtin_amdgcn_s_setprio(1); MFMA8(4); __builtin_amdgcn_s_setprio(0);    \
    __builtin_amdgcn_s_barrier();                                              \
    /* phase 3 */                                                              \
    aA_ = LDA(bb_, 6); aB_ = LDA(bb_, 7);                                      \
    if (STEN) STAGE1((kt_) + 3, 3);                                            \
    VMLINE;                                                                    \
    __builtin_amdgcn_s_barrier();                                              \
    asm volatile("s_waitcnt lgkmcnt(0)" ::: "memory");                         \
    __builtin_amdgcn_s_setprio(1); MFMA8(6); __builtin_amdgcn_s_setprio(0);    \
    __builtin_amdgcn_s_barrier();                                              \
} while (0)

    // accumulators: 8 m-frags (codes) x 4 n-frags (points); init = -wsq/2
    f32x4 acc[8][4];
#pragma unroll
    for (int mf = 0; mf < 8; ++mf) {
#pragma unroll
        for (int r = 0; r < 4; ++r) {
            float hv = -0.5f * wsq[kc0 + wm * 128 + mf * 16 + ((l >> 4) << 2) + r];
#pragma unroll
            for (int nf = 0; nf < 4; ++nf) acc[mf][nf][r] = hv;
        }
    }

    // prologue: stage K-tiles 0,1,2 (12 loads/wave); wait tile 0 (8 in flight)
    STAGE4(0);
    STAGE4(1);
    STAGE4(2);
    asm volatile("s_waitcnt vmcnt(8)" ::: "memory");
    __builtin_amdgcn_s_barrier();

    // main loop: 4-phase compute of kt, staging kt+3 spread across phases,
    // counted vmcnt(8) at phase 3 (tile kt+1 resident before its reads)
    for (int kt = 0; kt < 21; ++kt) {
        KTILE(kt, 1, asm volatile("s_waitcnt vmcnt(8)" ::: "memory"));
    }
    // drain: tiles 21, 22, 23
    KTILE(21, 0, asm volatile("s_waitcnt vmcnt(4)" ::: "memory"));
    KTILE(22, 0, asm volatile("s_waitcnt vmcnt(0)" ::: "memory"));
    KTILE(23, 0, ((void)0));

    // ---- top-2 screen epilogue (s-space: dv = -acc, smaller = better) ----
    float v1[4], v2[4];
    int k1[4];
#pragma unroll
    for (int nf = 0; nf < 4; ++nf) { v1[nf] = 3.4e38f; v2[nf] = 3.4e38f; k1[nf] = 0; }
#pragma unroll
    for (int mf = 0; mf < 8; ++mf) {
#pragma unroll
        for (int r = 0; r < 4; ++r) {
            int code = kc0 + wm * 128 + mf * 16 + ((l >> 4) << 2) + r;
#pragma unroll
            for (int nf = 0; nf < 4; ++nf) {
                float dv = -acc[mf][nf][r];
                bool lt = dv < v1[nf];
                v2[nf] = fminf(v2[nf], fmaxf(v1[nf], dv));
                v1[nf] = fminf(v1[nf], dv);
                k1[nf] = lt ? code : k1[nf];
            }
        }
    }
    // merge across the 4 row-groups (lanes l, l^16, l^32, l^48 share cols)
#pragma unroll
    for (int nf = 0; nf < 4; ++nf) {
#pragma unroll
        for (int mask = 16; mask <= 32; mask <<= 1) {
            float ov1 = __shfl_xor(v1[nf], mask, 64);
            float ov2 = __shfl_xor(v2[nf], mask, 64);
            int ok1 = __shfl_xor(k1[nf], mask, 64);
            bool take = (ov1 < v1[nf]) || (ov1 == v1[nf] && ok1 < k1[nf]);
            if (take) { v2[nf] = fminf(v1[nf], ov2); v1[nf] = ov1; k1[nf] = ok1; }
            else v2[nf] = fminf(v2[nf], ov1);
        }
    }
    __syncthreads();  // pipeline fully done; reuse LDS for cross-wave merge
    float* sv1 = (float*)sAB;            // [256][2]
    float* sv2 = sv1 + 512;              // [256][2]
    int* sk1 = (int*)(sv2 + 512);        // [256][2]
    if ((l >> 4) == 0) {
#pragma unroll
        for (int nf = 0; nf < 4; ++nf) {
            int col = wn * 64 + nf * 16 + l;
            sv1[col * 2 + wm] = v1[nf];
            sv2[col * 2 + wm] = v2[nf];
            sk1[col * 2 + wm] = k1[nf];
        }
    }
    __syncthreads();
    if (t < 256) {
        float a1 = sv1[t * 2], b1 = sv1[t * 2 + 1];
        float a2 = sv2[t * 2], b2 = sv2[t * 2 + 1];
        int ak = sk1[t * 2], bk = sk1[t * 2 + 1];
        bool tb = (b1 < a1) || (b1 == a1 && bk < ak);
        float w1 = tb ? b1 : a1;
        int wk = tb ? bk : ak;
        float w2 = tb ? fminf(b2, a1) : fminf(a2, b1);
        pv1[blockIdx.y * NP + n0 + t] = w1;
        pv2[blockIdx.y * NP + n0 + t] = w2;
        pk1[blockIdx.y * NP + n0 + t] = wk;
    }
#undef STAGE1
#undef STAGE4
#undef LDA
#undef LDB
#undef MFMA8
#undef KTILE
}

// merge 32 partials per point; compact ambiguous rows for exact rescore
__global__ __launch_bounds__(256) void merge_top2(
    const float* __restrict__ pv1, const float* __restrict__ pv2,
    const int* __restrict__ pk1, int* __restrict__ idxw, int* __restrict__ flag,
    int* __restrict__ list, int* __restrict__ nflag,
    unsigned long long* __restrict__ packed) {
    int n = blockIdx.x * 256 + threadIdx.x;
    float gv1 = 3.4e38f, gv2 = 3.4e38f;
    int gk1 = 0;
#pragma unroll
    for (int ct = 0; ct < NPART; ++ct) {
        float v1 = pv1[ct * NP + n];
        if (v1 < gv1) {
            gv2 = fminf(gv1, pv2[ct * NP + n]);
            gv1 = v1;
            gk1 = pk1[ct * NP + n];
        } else {
            gv2 = fminf(gv2, v1);
        }
    }
    idxw[n] = gk1;
    int f = (gv2 - gv1 < MARGIN_S) ? 1 : 0;
    flag[n] = f;
    if (f) {
        packed[n] = 0xFFFFFFFFFFFFFFFFull;
        int pos = atomicAdd(nflag, 1);
        list[pos] = n;
    }
}

// exact fp32 rescore of flagged rows, wave-cooperative (lanes along D).
__global__ __launch_bounds__(256) void rescore_par(
    const float* __restrict__ z, const float* __restrict__ cb,
    const float* __restrict__ nrm, const float* __restrict__ wsq,
    const float* __restrict__ zsq, const int* __restrict__ list,
    const int* __restrict__ nflag, unsigned long long* __restrict__ packed) {
    __shared__ float sz[256];
    int nf = *nflag;
    int t = threadIdx.x;
    int lane = t & 63, wv = t >> 6;
    for (int ii = blockIdx.x; ii < nf; ii += 64) {
        int n = list[ii];
        int b = n >> 10, hw = n & 1023;
        __syncthreads();
        sz[t] = z[(b * DD + t) * 1024 + hw];
        __syncthreads();
        float4 zr = ((const float4*)sz)[lane];
        float zq = zsq[n];
        unsigned long long best = 0xFFFFFFFFFFFFFFFFull;
        int kbase = blockIdx.y * 256 + wv * 64;
        for (int j = 0; j < 64; ++j) {
            int k = kbase + j;
            float4 cc = *(const float4*)&cb[(size_t)k * DD + lane * 4];
            float p = (zr.x * cc.x + zr.y * cc.y) + (zr.z * cc.z + zr.w * cc.w);
#pragma unroll
            for (int off = 32; off; off >>= 1) p += __shfl_xor(p, off, 64);
            float dot = p / nrm[k];
            float dv = (zq + wsq[k]) - 2.0f * dot;
            unsigned bits = __float_as_uint(dv);
            bits = (bits & 0x80000000u) ? ~bits : (bits | 0x80000000u);
            unsigned long long pk = ((unsigned long long)bits << 32) | (unsigned)k;
            best = best < pk ? best : pk;
        }
        if (lane == 0) atomicMin(packed + n, best);
    }
}

// apply rescored winners + idx out (float) + histogram
__global__ __launch_bounds__(256) void fix_hist(
    const int* __restrict__ flag, const unsigned long long* __restrict__ packed,
    int* __restrict__ idxw, float* __restrict__ out, int* __restrict__ hist) {
    int n = blockIdx.x * 256 + threadIdx.x;
    int k = flag[n] ? (int)(packed[n] & 0xFFFFFFFFull) : idxw[n];
    idxw[n] = k;
    out[ZQ_ELEMS + n] = (float)k;
    atomicAdd(&hist[k], 1);
}

// z_q gather (w = cb/nrm, identical rounding to prep) + per-block loss partial
__global__ __launch_bounds__(256) void gather_loss(
    const float* __restrict__ z, const float* __restrict__ cb,
    const float* __restrict__ nrm, const int* __restrict__ idxw,
    float* __restrict__ out, double* __restrict__ lossp) {
    __shared__ double lred[4];
    int t = threadIdx.x;
    int base = (blockIdx.x * 256 + t) * 16;
    double s = 0.0;
#pragma unroll
    for (int q = 0; q < 4; ++q) {
        int e = base + q * 4;
        int b = e >> 18, d = (e >> 10) & 255, hw = e & 1023;
        int n = (b << 10) + hw;
        float4 zv = *(const float4*)&z[e];
        float o[4];
#pragma unroll
        for (int j = 0; j < 4; ++j) {
            int k = idxw[n + j];
            o[j] = cb[k * DD + d] / nrm[k];
        }
        *(float4*)&out[e] = make_float4(o[0], o[1], o[2], o[3]);
        float d0 = o[0] - zv.x, d1 = o[1] - zv.y, d2 = o[2] - zv.z, d3 = o[3] - zv.w;
        s += (double)(d0 * d0) + (double)(d1 * d1) + (double)(d2 * d2) + (double)(d3 * d3);
    }
    s = waveReduceD(s);
    int lane = t & 63, wid = t >> 6;
    if (lane == 0) lred[wid] = s;
    __syncthreads();
    if (t == 0) lossp[blockIdx.x] = lred[0] + lred[1] + lred[2] + lred[3];
}

// single block: loss from 512 partials + perplexity from histogram
__global__ __launch_bounds__(256) void finalize_kernel(
    const int* __restrict__ hist, const double* __restrict__ lossp,
    float* __restrict__ out) {
    __shared__ double lred[4];
    __shared__ double lsum;
    int t = threadIdx.x;
    int lane = t & 63, wid = t >> 6;
    double ls = lossp[t] + lossp[t + 256];
    ls = waveReduceD(ls);
    if (lane == 0) lred[wid] = ls;
    __syncthreads();
    if (t == 0) lsum = lred[0] + lred[1] + lred[2] + lred[3];
    __syncthreads();
    double s = 0.0;
    for (int i = t; i < KC; i += 256) {
        float p = (float)hist[i] * (1.0f / 8192.0f);
        float lg = logf(p + 1e-10f);
        s += (double)(p * lg);
    }
    s = waveReduceD(s);
    if (lane == 0) lred[wid] = s;
    __syncthreads();
    if (t == 0) {
        double tot = lred[0] + lred[1] + lred[2] + lred[3];
        float m = (float)(lsum / (double)ZQ_ELEMS);
        out[ZQ_ELEMS + NP] = m + 0.25f * m;
        out[ZQ_ELEMS + NP + 1] = expf(-(float)tot);
    }
}

extern "C" void kernel_launch(void* const* d_in, const int* in_sizes, int n_in,
                              void* d_out, int out_size, void* d_ws, size_t ws_size,
                              hipStream_t stream) {
    const float* z = (const float*)d_in[0];
    const float* cb = (const float*)d_in[1];
    float* out = (float*)d_out;
    char* ws = (char*)d_ws;

    unsigned short* Abig = (unsigned short*)(ws + OFF_ABIG);
    unsigned short* Bbig = (unsigned short*)(ws + OFF_BBIG);
    float* nrm = (float*)(ws + OFF_NRM);
    float* wsq = (float*)(ws + OFF_WSQ);
    float* zsq = (float*)(ws + OFF_ZSQ);
    float* pv1 = (float*)(ws + OFF_PV1);
    float* pv2 = (float*)(ws + OFF_PV2);
    int* pk1 = (int*)(ws + OFF_PK1);
    int* idxw = (int*)(ws + OFF_IDX);
    int* flag = (int*)(ws + OFF_FLAG);
    int* hist = (int*)(ws + OFF_HIST);
    double* lossp = (double*)(ws + OFF_LOSSP);
    unsigned long long* packed = (unsigned long long*)(ws + OFF_PACK);
    int* list = (int*)(ws + OFF_LIST);
    int* nflag = (int*)(ws + OFF_NFLG);

    prep<<<2 * KC, 256, 0, stream>>>(cb, z, Bbig, Abig, nrm, wsq, zsq, hist, nflag);
    gemm_top2<<<dim3(32, NPART), 512, 0, stream>>>(Abig, Bbig, wsq, pv1, pv2, pk1);
    merge_top2<<<NP / 256, 256, 0, stream>>>(pv1, pv2, pk1, idxw, flag, list, nflag, packed);
    rescore_par<<<dim3(64, 32), 256, 0, stream>>>(z, cb, nrm, wsq, zsq, list, nflag, packed);
    fix_hist<<<NP / 256, 256, 0, stream>>>(flag, packed, idxw, out, hist);
    gather_loss<<<ZQ_ELEMS / (256 * 16), 256, 0, stream>>>(z, cb, nrm, idxw, out, lossp);
    finalize_kernel<<<1, 256, 0, stream>>>(hist, lossp, out);
}